// Round 2
// baseline (799.002 us; speedup 1.0000x reference)
//
#include <hip/hip_runtime.h>
#include <math.h>

// ---------------------------------------------------------------------------
// EncoderBlock (QANet-style) fp32 implementation for MI355X.
// B=16, C=128, L=1024, H=8, DK=16, K=7, NCONV=4.
//
// R1 change: k_attn restructured. Old: 512 blocks (8 waves/CU, 21% occ),
// 1024-key serial loop per thread with a 16-deep dependent dot chain ->
// latency-bound at 490us. New: keys split 4-way across the block's 4 waves
// (no-max softmax => partials combine additively), grid 2048 blocks ->
// 32 waves/CU, dot chain split 4-way. Predicted 75-110us.
// ---------------------------------------------------------------------------

#define CC 128
#define LL 1024
#define NEGF (-1e30f)

// ---------------- ws layout (floats) ----------------
#define ACT_N   2097152
#define OFF_ACT0 0
#define OFF_ACT1 (ACT_N)
#define OFF_QW   (2*ACT_N)
#define OFF_KW   (3*ACT_N)
#define OFF_VW   (4*ACT_N)
#define OFF_AB   (5*ACT_N)
#define OFF_WT   (6*ACT_N)
#define OFF_MF   (6*ACT_N + 10*16384)

// ---------------------------------------------------------------------------
// k_prep: blocks 0..39 transpose (10 mats x 4 row-groups of 32), 40..47 maskf
// ---------------------------------------------------------------------------
__global__ __launch_bounds__(256) void k_prep(
    const float* __restrict__ pw, const float* __restrict__ wq,
    const float* __restrict__ wk, const float* __restrict__ wv_,
    const float* __restrict__ wo, const float* __restrict__ w1,
    const float* __restrict__ w2, const unsigned char* __restrict__ mask,
    float* __restrict__ wT, float* __restrict__ maskf)
{
    __shared__ float td[32][33];
    int blk = blockIdx.x;
    int t = threadIdx.x;
    if (blk < 40) {
        int mat = blk >> 2, og = blk & 3;
        const float* src;
        if (mat < 4)      src = pw + mat * 16384;
        else if (mat == 4) src = wq;
        else if (mat == 5) src = wk;
        else if (mat == 6) src = wv_;
        else if (mat == 7) src = wo;
        else if (mat == 8) src = w1;
        else               src = w2;
        float* dst = wT + mat * 16384;
        for (int cg = 0; cg < 4; ++cg) {
            for (int i = t; i < 1024; i += 256) {
                int o = i >> 5, c = i & 31;
                td[o][c] = src[(og * 32 + o) * 128 + cg * 32 + c];
            }
            __syncthreads();
            for (int i = t; i < 1024; i += 256) {
                int c = i >> 5, oo = i & 31;
                dst[(cg * 32 + c) * 128 + og * 32 + oo] = td[oo][c];
            }
            __syncthreads();
        }
    } else {
        int base = (blk - 40) * 2048;
        for (int i = t; i < 2048; i += 256)
            maskf[base + i] = mask[base + i] ? NEGF : 3.0e38f;
    }
}

// ---------------------------------------------------------------------------
// k_pe: out = x + sin(l*freq(c) + phase(c))
// ---------------------------------------------------------------------------
__global__ __launch_bounds__(256) void k_pe(const float* __restrict__ x,
                                            float* __restrict__ out)
{
    int idx = blockIdx.x * 256 + threadIdx.x;   // < 2097152
    int l = idx & 1023;
    int c = (idx >> 10) & 127;
    float e = (float)(c & ~1);
    float base = exp2f(e * (-13.287712379549449f / 128.0f));
    float freq = (c & 1) ? -base : base;
    float ph   = (c & 1) ? 1.5707963267948966f : 0.0f;
    out[idx] = x[idx] + sinf((float)l * freq + ph);
}

// ---------------------------------------------------------------------------
// k_conv: one conv block. grid 256 (b,tile), 512 threads (8 waves).
// ---------------------------------------------------------------------------
__global__ __launch_bounds__(512) void k_conv(
    const float* __restrict__ in, float* __restrict__ out,
    const float* __restrict__ wT,                 // [128 c][128 o]
    const float* __restrict__ dw,                 // [128][7]
    const float* __restrict__ pb,                 // [128]
    const float* __restrict__ g, const float* __restrict__ nbv)
{
    __shared__ float xs[128 * 70];   // LN'd input tile with halo of 3
    __shared__ float ys[128 * 64];   // depthwise output
    const int b  = blockIdx.x >> 4;
    const int l0 = (blockIdx.x & 15) << 6;
    const int t  = threadIdx.x;
    const int lane = t & 63;
    const int wv = __builtin_amdgcn_readfirstlane(t >> 6);   // 0..7
    const float* xb = in + b * 131072;

    for (int i = t; i < 128 * 70; i += 512) {
        int c = i / 70;
        int col = i - c * 70;
        int gl = l0 - 3 + col;
        xs[i] = ((unsigned)gl < 1024u) ? xb[c * 1024 + gl] : 0.0f;
    }
    __syncthreads();

    if (t < 70) {
        int gl = l0 - 3 + t;
        if ((unsigned)gl < 1024u) {
            float s = 0.f, ss = 0.f;
            for (int c = 0; c < 128; ++c) {
                float v = xs[c * 70 + t];
                s += v; ss = fmaf(v, v, ss);
            }
            float mu = s * 0.0078125f;
            float var = ss * 0.0078125f - mu * mu;
            float rs = rsqrtf(var + 1e-5f);
            for (int c = 0; c < 128; ++c) {
                xs[c * 70 + t] = (xs[c * 70 + t] - mu) * rs * g[c] + nbv[c];
            }
        }
    }
    __syncthreads();

    for (int cc = 0; cc < 16; ++cc) {
        int c = (wv << 4) + cc;
        const float* dr = dw + c * 7;           // wave-uniform
        const float* xr = xs + c * 70 + lane;
        float a =          dr[0] * xr[0];
        a = fmaf(dr[1], xr[1], a);
        a = fmaf(dr[2], xr[2], a);
        a = fmaf(dr[3], xr[3], a);
        a = fmaf(dr[4], xr[4], a);
        a = fmaf(dr[5], xr[5], a);
        a = fmaf(dr[6], xr[6], a);
        ys[c * 64 + lane] = a;
    }
    __syncthreads();

    const int ow = wv << 4;
    const float* wTb = wT + ow;
    float acc[16];
    #pragma unroll
    for (int j = 0; j < 16; ++j) acc[j] = 0.f;
    #pragma unroll 4
    for (int c = 0; c < 128; ++c) {
        float y = ys[c * 64 + lane];
        #pragma unroll
        for (int j = 0; j < 16; ++j)
            acc[j] = fmaf(wTb[c * 128 + j], y, acc[j]);
    }

    float* ob = out + b * 131072;
    #pragma unroll
    for (int j = 0; j < 16; ++j) {
        int o = ow + j;
        float v = fmaxf(acc[j] + pb[o], 0.f) + xb[o * 1024 + l0 + lane];
        ob[o * 1024 + l0 + lane] = v;
    }
}

// ---------------------------------------------------------------------------
// k_qkv: LN + 3 GEMMs; outputs [B,H,L,DK] (wave wv == head wv)
// ---------------------------------------------------------------------------
__global__ __launch_bounds__(512) void k_qkv(
    const float* __restrict__ in, const float* __restrict__ wT, // wq|wk|wv T
    const float* __restrict__ bq, const float* __restrict__ bk,
    const float* __restrict__ bv,
    const float* __restrict__ g, const float* __restrict__ nbv,
    float* __restrict__ qw, float* __restrict__ kw, float* __restrict__ vw)
{
    __shared__ float ln[128 * 64];
    __shared__ float st[8 * 16 * 66];       // per-wave transpose bounce
    const int b  = blockIdx.x >> 4;
    const int l0 = (blockIdx.x & 15) << 6;
    const int t  = threadIdx.x;
    const int lane = t & 63;
    const int wv = __builtin_amdgcn_readfirstlane(t >> 6);
    const float* xb = in + b * 131072;

    for (int i = t; i < 8192; i += 512) {
        int c = i >> 6, col = i & 63;
        ln[i] = xb[c * 1024 + l0 + col];
    }
    __syncthreads();
    if (t < 64) {
        float s = 0.f, ss = 0.f;
        for (int c = 0; c < 128; ++c) {
            float v = ln[c * 64 + t];
            s += v; ss = fmaf(v, v, ss);
        }
        float mu = s * 0.0078125f;
        float var = ss * 0.0078125f - mu * mu;
        float rs = rsqrtf(var + 1e-5f);
        for (int c = 0; c < 128; ++c)
            ln[c * 64 + t] = (ln[c * 64 + t] - mu) * rs * g[c] + nbv[c];
    }
    __syncthreads();

    const int ow = wv << 4;
    const int dq = lane & 3, l2 = lane >> 2;
    for (int pass = 0; pass < 3; ++pass) {
        const float* wTb = wT + pass * 16384 + ow;
        const float* bias = (pass == 0) ? bq : (pass == 1) ? bk : bv;
        float* outp = (pass == 0) ? qw : (pass == 1) ? kw : vw;
        float acc[16];
        #pragma unroll
        for (int j = 0; j < 16; ++j) acc[j] = 0.f;
        #pragma unroll 4
        for (int c = 0; c < 128; ++c) {
            float y = ln[c * 64 + lane];
            #pragma unroll
            for (int j = 0; j < 16; ++j)
                acc[j] = fmaf(wTb[c * 128 + j], y, acc[j]);
        }
        float* stw = st + wv * 1056;
        #pragma unroll
        for (int j = 0; j < 16; ++j)
            stw[j * 66 + lane] = acc[j] + bias[ow + j];
        float* op = outp + ((size_t)(b * 8 + wv) * 1024 + l0) * 16;
        #pragma unroll
        for (int r = 0; r < 4; ++r) {
            int llx = l2 + (r << 4);
            float4 pk;
            pk.x = stw[(dq * 4 + 0) * 66 + llx];
            pk.y = stw[(dq * 4 + 1) * 66 + llx];
            pk.z = stw[(dq * 4 + 2) * 66 + llx];
            pk.w = stw[(dq * 4 + 3) * 66 + llx];
            *(float4*)(op + llx * 16 + dq * 4) = pk;
        }
    }
}

// ---------------------------------------------------------------------------
// k_attn (R1): grid 2048 = (b,h) x 16 query-chunks of 64; 256 thr = 4 waves.
// Thread (ql, kp): query ql of chunk, key-quarter kp (256 keys).
// No-max softmax => per-quarter partials (sum, acc[16]) combine additively
// in LDS. 32 waves/CU. Dot chain split into 4 independent 4-deep chains.
// ---------------------------------------------------------------------------
__global__ __launch_bounds__(256) void k_attn(
    const float* __restrict__ q, const float* __restrict__ k,
    const float* __restrict__ v, const float* __restrict__ mfv,
    float* __restrict__ ab)
{
    __shared__ float accP[4][64][18];   // [kp][ql][0..15]=acc, [16]=sum
    const int bh = blockIdx.x >> 4;
    const int b  = bh >> 3;
    const int h  = bh & 7;
    const int qc = blockIdx.x & 15;
    const int t  = threadIdx.x;
    const int ql = t & 63;
    const int kp = t >> 6;              // 0..3 key-quarter
    const int l  = qc * 64 + ql;

    const float* qr = q + ((size_t)bh * 1024 + l) * 16;
    const float* kr = k + (size_t)bh * 16384 + kp * 4096;
    const float* vr = v + (size_t)bh * 16384 + kp * 4096;
    const float* mf = mfv + b * 1024 + kp * 256;

    float qv[16];
    #pragma unroll
    for (int d = 0; d < 16; ++d) qv[d] = qr[d] * 0.25f;   // fold 1/sqrt(DK)

    float acc[16];
    #pragma unroll
    for (int d = 0; d < 16; ++d) acc[d] = 0.f;
    float sum = 0.f;

    float ka[16], va[16], ma;
    float kb2[16], vb2[16], mb2;

#define LOADKV(K, V, M, idx) { \
        const float* _kp = kr + (idx) * 16; const float* _vp = vr + (idx) * 16; \
        _Pragma("unroll") for (int d = 0; d < 16; ++d) { K[d] = _kp[d]; V[d] = _vp[d]; } \
        M = mf[idx]; }
#define STEPKV(K, V, M) { \
        float s0 = qv[0] * K[0]; float s1 = qv[1] * K[1]; \
        float s2 = qv[2] * K[2]; float s3 = qv[3] * K[3]; \
        s0 = fmaf(qv[4],  K[4],  s0); s1 = fmaf(qv[5],  K[5],  s1); \
        s2 = fmaf(qv[6],  K[6],  s2); s3 = fmaf(qv[7],  K[7],  s3); \
        s0 = fmaf(qv[8],  K[8],  s0); s1 = fmaf(qv[9],  K[9],  s1); \
        s2 = fmaf(qv[10], K[10], s2); s3 = fmaf(qv[11], K[11], s3); \
        s0 = fmaf(qv[12], K[12], s0); s1 = fmaf(qv[13], K[13], s1); \
        s2 = fmaf(qv[14], K[14], s2); s3 = fmaf(qv[15], K[15], s3); \
        float s = (s0 + s1) + (s2 + s3); \
        s = fminf(s, M); \
        float p = __expf(s); \
        sum += p; \
        _Pragma("unroll") for (int d = 0; d < 16; ++d) acc[d] = fmaf(p, V[d], acc[d]); }

    LOADKV(ka, va, ma, 0)
    for (int m = 0; m < 256; m += 2) {
        LOADKV(kb2, vb2, mb2, m + 1)
        STEPKV(ka, va, ma)
        int m2 = (m + 2 <= 255) ? (m + 2) : 255;
        LOADKV(ka, va, ma, m2)
        STEPKV(kb2, vb2, mb2)
    }
#undef LOADKV
#undef STEPKV

    #pragma unroll
    for (int d = 0; d < 16; ++d) accP[kp][ql][d] = acc[d];
    accP[kp][ql][16] = sum;
    __syncthreads();

    float st = accP[0][ql][16] + accP[1][ql][16]
             + accP[2][ql][16] + accP[3][ql][16];
    float inv = 1.0f / (st + 1e-37f);
    float* op = ab + ((size_t)b * 128 + h * 16) * 1024 + l;
    #pragma unroll
    for (int j = 0; j < 4; ++j) {
        int d = kp * 4 + j;
        float a = accP[0][ql][d] + accP[1][ql][d]
                + accP[2][ql][d] + accP[3][ql][d];
        op[(size_t)d * 1024] = a * inv;
    }
}

// ---------------------------------------------------------------------------
// k_oproj: GEMM(wo) + bias + residual
// ---------------------------------------------------------------------------
__global__ __launch_bounds__(512) void k_oproj(
    const float* __restrict__ in, const float* __restrict__ wT,
    const float* __restrict__ bo, const float* __restrict__ res,
    float* __restrict__ out)
{
    __shared__ float as[128 * 64];
    const int b  = blockIdx.x >> 4;
    const int l0 = (blockIdx.x & 15) << 6;
    const int t  = threadIdx.x;
    const int lane = t & 63;
    const int wv = __builtin_amdgcn_readfirstlane(t >> 6);
    const float* xb = in + b * 131072;

    for (int i = t; i < 8192; i += 512) {
        int c = i >> 6, col = i & 63;
        as[i] = xb[c * 1024 + l0 + col];
    }
    __syncthreads();

    const int ow = wv << 4;
    const float* wTb = wT + ow;
    float acc[16];
    #pragma unroll
    for (int j = 0; j < 16; ++j) acc[j] = 0.f;
    #pragma unroll 4
    for (int c = 0; c < 128; ++c) {
        float y = as[c * 64 + lane];
        #pragma unroll
        for (int j = 0; j < 16; ++j)
            acc[j] = fmaf(wTb[c * 128 + j], y, acc[j]);
    }
    const float* rb = res + b * 131072;
    float* ob = out + b * 131072;
    #pragma unroll
    for (int j = 0; j < 16; ++j) {
        int o = ow + j;
        ob[o * 1024 + l0 + lane] = acc[j] + bo[o] + rb[o * 1024 + l0 + lane];
    }
}

// ---------------------------------------------------------------------------
// k_ffn: LN -> GEMM(w1)+ReLU -> GEMM(w2) + bias + residual -> d_out
// ---------------------------------------------------------------------------
__global__ __launch_bounds__(512) void k_ffn(
    const float* __restrict__ in,
    const float* __restrict__ w1T, const float* __restrict__ w2T,
    const float* __restrict__ b1, const float* __restrict__ b2,
    const float* __restrict__ g, const float* __restrict__ nbv,
    float* __restrict__ out)
{
    __shared__ float ln[128 * 64];    // LN result, then reused for hidden h
    const int b  = blockIdx.x >> 4;
    const int l0 = (blockIdx.x & 15) << 6;
    const int t  = threadIdx.x;
    const int lane = t & 63;
    const int wv = __builtin_amdgcn_readfirstlane(t >> 6);
    const float* xb = in + b * 131072;

    for (int i = t; i < 8192; i += 512) {
        int c = i >> 6, col = i & 63;
        ln[i] = xb[c * 1024 + l0 + col];
    }
    __syncthreads();
    if (t < 64) {
        float s = 0.f, ss = 0.f;
        for (int c = 0; c < 128; ++c) {
            float v = ln[c * 64 + t];
            s += v; ss = fmaf(v, v, ss);
        }
        float mu = s * 0.0078125f;
        float var = ss * 0.0078125f - mu * mu;
        float rs = rsqrtf(var + 1e-5f);
        for (int c = 0; c < 128; ++c)
            ln[c * 64 + t] = (ln[c * 64 + t] - mu) * rs * g[c] + nbv[c];
    }
    __syncthreads();

    const int ow = wv << 4;
    float acc[16];
    #pragma unroll
    for (int j = 0; j < 16; ++j) acc[j] = 0.f;
    {
        const float* wTb = w1T + ow;
        #pragma unroll 4
        for (int c = 0; c < 128; ++c) {
            float y = ln[c * 64 + lane];
            #pragma unroll
            for (int j = 0; j < 16; ++j)
                acc[j] = fmaf(wTb[c * 128 + j], y, acc[j]);
        }
    }
    __syncthreads();
    #pragma unroll
    for (int j = 0; j < 16; ++j)
        ln[(ow + j) * 64 + lane] = fmaxf(acc[j] + b1[ow + j], 0.f);
    __syncthreads();
    #pragma unroll
    for (int j = 0; j < 16; ++j) acc[j] = 0.f;
    {
        const float* wTb = w2T + ow;
        #pragma unroll 4
        for (int c = 0; c < 128; ++c) {
            float y = ln[c * 64 + lane];
            #pragma unroll
            for (int j = 0; j < 16; ++j)
                acc[j] = fmaf(wTb[c * 128 + j], y, acc[j]);
        }
    }
    float* ob = out + b * 131072;
    #pragma unroll
    for (int j = 0; j < 16; ++j) {
        int o = ow + j;
        ob[o * 1024 + l0 + lane] = acc[j] + b2[o] + xb[o * 1024 + l0 + lane];
    }
}

// ---------------------------------------------------------------------------
extern "C" void kernel_launch(void* const* d_in, const int* in_sizes, int n_in,
                              void* d_out, int out_size, void* d_ws, size_t ws_size,
                              hipStream_t stream)
{
    const float* x    = (const float*)d_in[0];
    const unsigned char* mask = (const unsigned char*)d_in[1];
    const float* dw_w = (const float*)d_in[2];
    const float* pw_w = (const float*)d_in[3];
    const float* pw_b = (const float*)d_in[4];
    const float* ng   = (const float*)d_in[5];
    const float* nb   = (const float*)d_in[6];
    const float* wq   = (const float*)d_in[7];
    const float* bq   = (const float*)d_in[8];
    const float* wk   = (const float*)d_in[9];
    const float* bk   = (const float*)d_in[10];
    const float* wv   = (const float*)d_in[11];
    const float* bv   = (const float*)d_in[12];
    const float* wo   = (const float*)d_in[13];
    const float* bo   = (const float*)d_in[14];
    const float* w1   = (const float*)d_in[15];
    const float* b1   = (const float*)d_in[16];
    const float* w2   = (const float*)d_in[17];
    const float* b2   = (const float*)d_in[18];

    float* ws   = (float*)d_ws;
    float* act0 = ws + OFF_ACT0;
    float* act1 = ws + OFF_ACT1;
    float* qw   = ws + OFF_QW;
    float* kw   = ws + OFF_KW;
    float* vw   = ws + OFF_VW;
    float* ab   = ws + OFF_AB;
    float* wT   = ws + OFF_WT;
    float* mf   = ws + OFF_MF;

    k_prep<<<48, 256, 0, stream>>>(pw_w, wq, wk, wv, wo, w1, w2, mask, wT, mf);
    k_pe<<<8192, 256, 0, stream>>>(x, act0);

    k_conv<<<256, 512, 0, stream>>>(act0, act1, wT + 0 * 16384, dw_w + 0,
                                    pw_b + 0,   ng + 0,   nb + 0);
    k_conv<<<256, 512, 0, stream>>>(act1, act0, wT + 1 * 16384, dw_w + 896,
                                    pw_b + 128, ng + 128, nb + 128);
    k_conv<<<256, 512, 0, stream>>>(act0, act1, wT + 2 * 16384, dw_w + 1792,
                                    pw_b + 256, ng + 256, nb + 256);
    k_conv<<<256, 512, 0, stream>>>(act1, act0, wT + 3 * 16384, dw_w + 2688,
                                    pw_b + 384, ng + 384, nb + 384);

    k_qkv<<<256, 512, 0, stream>>>(act0, wT + 4 * 16384, bq, bk, bv,
                                   ng + 4 * 128, nb + 4 * 128, qw, kw, vw);
    k_attn<<<2048, 256, 0, stream>>>(qw, kw, vw, mf, ab);
    k_oproj<<<256, 512, 0, stream>>>(ab, wT + 7 * 16384, bo, act0, act1);
    k_ffn<<<256, 512, 0, stream>>>(act1, wT + 8 * 16384, wT + 9 * 16384,
                                   b1, b2, ng + 5 * 128, nb + 5 * 128,
                                   (float*)d_out);
}

// Round 3
// 521.558 us; speedup vs baseline: 1.5320x; 1.5320x over previous
//
#include <hip/hip_runtime.h>
#include <math.h>

// ---------------------------------------------------------------------------
// EncoderBlock fp32, MI355X. B=16, C=128, L=1024, H=8, DK=16, K=7, NCONV=4.
// R2: all reused operands staged in LDS; inner loops = ds_read(broadcast)+fmac.
// ---------------------------------------------------------------------------

#define NEGF (-1e30f)

#define ACT_N   2097152
#define OFF_ACT0 0
#define OFF_ACT1 (ACT_N)
#define OFF_QW   (2*ACT_N)
#define OFF_KW   (3*ACT_N)
#define OFF_VW   (4*ACT_N)
#define OFF_AB   (5*ACT_N)
#define OFF_WT   (6*ACT_N)
#define OFF_MF   (6*ACT_N + 10*16384)
#define OFF_DW8  (6*ACT_N + 10*16384 + 16384)

__global__ __launch_bounds__(256) void k_prep(
    const float* __restrict__ pw, const float* __restrict__ wq,
    const float* __restrict__ wk, const float* __restrict__ wv_,
    const float* __restrict__ wo, const float* __restrict__ w1,
    const float* __restrict__ w2, const unsigned char* __restrict__ mask,
    const float* __restrict__ dwsrc,
    float* __restrict__ wT, float* __restrict__ maskf, float* __restrict__ dw8)
{
    __shared__ float td[32][33];
    int blk = blockIdx.x;
    int t = threadIdx.x;
    if (blk < 40) {
        int mat = blk >> 2, og = blk & 3;
        const float* src;
        if (mat < 4)      src = pw + mat * 16384;
        else if (mat == 4) src = wq;
        else if (mat == 5) src = wk;
        else if (mat == 6) src = wv_;
        else if (mat == 7) src = wo;
        else if (mat == 8) src = w1;
        else               src = w2;
        float* dst = wT + mat * 16384;
        for (int cg = 0; cg < 4; ++cg) {
            for (int i = t; i < 1024; i += 256) {
                int o = i >> 5, c = i & 31;
                td[o][c] = src[(og * 32 + o) * 128 + cg * 32 + c];
            }
            __syncthreads();
            for (int i = t; i < 1024; i += 256) {
                int c = i >> 5, oo = i & 31;
                dst[(cg * 32 + c) * 128 + og * 32 + oo] = td[oo][c];
            }
            __syncthreads();
        }
    } else if (blk < 48) {
        int base = (blk - 40) * 2048;
        for (int i = t; i < 2048; i += 256)
            maskf[base + i] = mask[base + i] ? NEGF : 3.0e38f;
    } else {
        for (int i = t; i < 4096; i += 256) {
            int n = i >> 3, tap = i & 7;
            dw8[i] = (tap < 7) ? dwsrc[n * 7 + tap] : 0.0f;
        }
    }
}

__global__ __launch_bounds__(256) void k_pe(const float* __restrict__ x,
                                            float* __restrict__ out)
{
    int idx = blockIdx.x * 256 + threadIdx.x;
    int l = idx & 1023;
    int c = (idx >> 10) & 127;
    float e = (float)(c & ~1);
    float base = exp2f(e * (-13.287712379549449f / 128.0f));
    float freq = (c & 1) ? -base : base;
    float ph   = (c & 1) ? 1.5707963267948966f : 0.0f;
    out[idx] = x[idx] + sinf((float)l * freq + ph);
}

__global__ __launch_bounds__(512) void k_conv(
    const float* __restrict__ in, float* __restrict__ out,
    const float* __restrict__ wT, const float* __restrict__ dw8,
    const float* __restrict__ pb,
    const float* __restrict__ g, const float* __restrict__ nbv)
{
    __shared__ float xs[128 * 70];
    __shared__ float wlds[128 * 128];
    __shared__ float dwl[128 * 8];
    __shared__ float part[70 * 8];
    __shared__ float muL[70], rsL[70];
    const int b  = blockIdx.x >> 4;
    const int l0 = (blockIdx.x & 15) << 6;
    const int t  = threadIdx.x;
    const int lane = t & 63;
    const int wv = t >> 6;
    const float* xb = in + b * 131072;

    {
        const float4* wsv = (const float4*)wT;
        float4* wd = (float4*)wlds;
        #pragma unroll
        for (int r = 0; r < 8; ++r) wd[t + r * 512] = wsv[t + r * 512];
        if (t < 256) ((float4*)dwl)[t] = ((const float4*)dw8)[t];
    }
    for (int i = t; i < 8960; i += 512) {
        int c = i / 70;
        int col = i - c * 70;
        int gl = l0 - 3 + col;
        xs[i] = ((unsigned)gl < 1024u) ? xb[c * 1024 + gl] : 0.0f;
    }
    __syncthreads();

    if (t < 280) {
        int col = t >> 2, sl = t & 3;
        float s = 0.f, ss = 0.f;
        for (int c = sl * 32; c < sl * 32 + 32; ++c) {
            float v = xs[c * 70 + col];
            s += v; ss = fmaf(v, v, ss);
        }
        part[col * 8 + sl * 2]     = s;
        part[col * 8 + sl * 2 + 1] = ss;
    }
    __syncthreads();
    if (t < 70) {
        float s  = part[t*8] + part[t*8+2] + part[t*8+4] + part[t*8+6];
        float ss = part[t*8+1] + part[t*8+3] + part[t*8+5] + part[t*8+7];
        float mu = s * 0.0078125f;
        float var = ss * 0.0078125f - mu * mu;
        muL[t] = mu;
        rsL[t] = rsqrtf(var + 1e-5f);
    }
    __syncthreads();
    for (int c = wv; c < 128; c += 8) {
        float gg = g[c], bb = nbv[c];
        int gl = l0 - 3 + lane;
        if ((unsigned)gl < 1024u) {
            float v = xs[c * 70 + lane];
            xs[c * 70 + lane] = (v - muL[lane]) * rsL[lane] * gg + bb;
        }
        if (lane < 6) {
            int col = 64 + lane;
            int gl2 = l0 - 3 + col;
            if ((unsigned)gl2 < 1024u) {
                float v = xs[c * 70 + col];
                xs[c * 70 + col] = (v - muL[col]) * rsL[col] * gg + bb;
            }
        }
    }
    __syncthreads();

    const int ow = wv << 4;
    float acc[16];
    #pragma unroll
    for (int j = 0; j < 16; ++j) acc[j] = 0.f;
    #pragma unroll 4
    for (int c = 0; c < 128; ++c) {
        const float* xr = xs + c * 70 + lane;
        const float4* dr = (const float4*)(dwl + c * 8);
        float4 d0 = dr[0], d1 = dr[1];
        float y =          d0.x * xr[0];
        y = fmaf(d0.y, xr[1], y);
        y = fmaf(d0.z, xr[2], y);
        y = fmaf(d0.w, xr[3], y);
        y = fmaf(d1.x, xr[4], y);
        y = fmaf(d1.y, xr[5], y);
        y = fmaf(d1.z, xr[6], y);
        const float4* wr = (const float4*)(wlds + c * 128 + ow);
        float4 w0 = wr[0], w1 = wr[1], w2 = wr[2], w3 = wr[3];
        acc[0]  = fmaf(w0.x, y, acc[0]);  acc[1]  = fmaf(w0.y, y, acc[1]);
        acc[2]  = fmaf(w0.z, y, acc[2]);  acc[3]  = fmaf(w0.w, y, acc[3]);
        acc[4]  = fmaf(w1.x, y, acc[4]);  acc[5]  = fmaf(w1.y, y, acc[5]);
        acc[6]  = fmaf(w1.z, y, acc[6]);  acc[7]  = fmaf(w1.w, y, acc[7]);
        acc[8]  = fmaf(w2.x, y, acc[8]);  acc[9]  = fmaf(w2.y, y, acc[9]);
        acc[10] = fmaf(w2.z, y, acc[10]); acc[11] = fmaf(w2.w, y, acc[11]);
        acc[12] = fmaf(w3.x, y, acc[12]); acc[13] = fmaf(w3.y, y, acc[13]);
        acc[14] = fmaf(w3.z, y, acc[14]); acc[15] = fmaf(w3.w, y, acc[15]);
    }

    float* ob = out + b * 131072;
    #pragma unroll
    for (int j = 0; j < 16; ++j) {
        int o = ow + j;
        float v = fmaxf(acc[j] + pb[o], 0.f) + xb[o * 1024 + l0 + lane];
        ob[o * 1024 + l0 + lane] = v;
    }
}

__global__ __launch_bounds__(512) void k_qkv(
    const float* __restrict__ in, const float* __restrict__ wT,
    const float* __restrict__ bq, const float* __restrict__ bk,
    const float* __restrict__ bv,
    const float* __restrict__ g, const float* __restrict__ nbv,
    float* __restrict__ qw, float* __restrict__ kw, float* __restrict__ vw)
{
    __shared__ float ln[128 * 64];
    __shared__ float wlds[128 * 128];
    __shared__ float part[64 * 8];
    __shared__ float muL[64], rsL[64];
    const int b  = blockIdx.x >> 4;
    const int l0 = (blockIdx.x & 15) << 6;
    const int t  = threadIdx.x;
    const int lane = t & 63;
    const int wv = t >> 6;
    const float* xb = in + b * 131072;

    {
        const float4* wsv = (const float4*)wT;
        float4* wd = (float4*)wlds;
        #pragma unroll
        for (int r = 0; r < 8; ++r) wd[t + r * 512] = wsv[t + r * 512];
    }
    for (int i = t; i < 8192; i += 512) {
        int c = i >> 6, col = i & 63;
        ln[i] = xb[c * 1024 + l0 + col];
    }
    __syncthreads();
    if (t < 256) {
        int col = t >> 2, sl = t & 3;
        float s = 0.f, ss = 0.f;
        for (int c = sl * 32; c < sl * 32 + 32; ++c) {
            float v = ln[c * 64 + col];
            s += v; ss = fmaf(v, v, ss);
        }
        part[col * 8 + sl * 2]     = s;
        part[col * 8 + sl * 2 + 1] = ss;
    }
    __syncthreads();
    if (t < 64) {
        float s  = part[t*8] + part[t*8+2] + part[t*8+4] + part[t*8+6];
        float ss = part[t*8+1] + part[t*8+3] + part[t*8+5] + part[t*8+7];
        float mu = s * 0.0078125f;
        float var = ss * 0.0078125f - mu * mu;
        muL[t] = mu;
        rsL[t] = rsqrtf(var + 1e-5f);
    }
    __syncthreads();
    for (int k = 0; k < 16; ++k) {
        int c = (t >> 6) + k * 8;
        float v = ln[c * 64 + lane];
        ln[c * 64 + lane] = (v - muL[lane]) * rsL[lane] * g[c] + nbv[c];
    }
    __syncthreads();

    const int ow = wv << 4;
    for (int p = 0; p < 3; ++p) {
        const float* bias = (p == 0) ? bq : (p == 1) ? bk : bv;
        float* outp = (p == 0) ? qw : (p == 1) ? kw : vw;
        float4 pw[8];
        if (p < 2) {
            const float4* wsv = (const float4*)(wT + (p + 1) * 16384);
            #pragma unroll
            for (int r = 0; r < 8; ++r) pw[r] = wsv[t + r * 512];
        }
        float acc[16];
        #pragma unroll
        for (int j = 0; j < 16; ++j) acc[j] = 0.f;
        #pragma unroll 4
        for (int c = 0; c < 128; ++c) {
            float y = ln[c * 64 + lane];
            const float4* wr = (const float4*)(wlds + c * 128 + ow);
            float4 w0 = wr[0], w1 = wr[1], w2 = wr[2], w3 = wr[3];
            acc[0]  = fmaf(w0.x, y, acc[0]);  acc[1]  = fmaf(w0.y, y, acc[1]);
            acc[2]  = fmaf(w0.z, y, acc[2]);  acc[3]  = fmaf(w0.w, y, acc[3]);
            acc[4]  = fmaf(w1.x, y, acc[4]);  acc[5]  = fmaf(w1.y, y, acc[5]);
            acc[6]  = fmaf(w1.z, y, acc[6]);  acc[7]  = fmaf(w1.w, y, acc[7]);
            acc[8]  = fmaf(w2.x, y, acc[8]);  acc[9]  = fmaf(w2.y, y, acc[9]);
            acc[10] = fmaf(w2.z, y, acc[10]); acc[11] = fmaf(w2.w, y, acc[11]);
            acc[12] = fmaf(w3.x, y, acc[12]); acc[13] = fmaf(w3.y, y, acc[13]);
            acc[14] = fmaf(w3.z, y, acc[14]); acc[15] = fmaf(w3.w, y, acc[15]);
        }
        float* op = outp + ((size_t)(b * 8 + wv) * 16) * 1024 + l0 + lane;
        #pragma unroll
        for (int j = 0; j < 16; ++j)
            op[(size_t)j * 1024] = acc[j] + bias[ow + j];
        __syncthreads();
        if (p < 2) {
            float4* wd = (float4*)wlds;
            #pragma unroll
            for (int r = 0; r < 8; ++r) wd[t + r * 512] = pw[r];
        }
        __syncthreads();
    }
}

__global__ __launch_bounds__(512) void k_attn(
    const float* __restrict__ q, const float* __restrict__ k,
    const float* __restrict__ v, const float* __restrict__ mfv,
    float* __restrict__ ab)
{
    __shared__ float kt[2][64 * 20];
    __shared__ float vt[2][64 * 20];
    __shared__ float mt[2][64];
    const int bh = blockIdx.x >> 1;
    const int b  = bh >> 3;
    const int h  = bh & 7;
    const int t  = threadIdx.x;
    const int qi = ((blockIdx.x & 1) << 9) + t;

    const float* qp = q + (size_t)bh * 16384;
    const float* kp = k + (size_t)bh * 16384;
    const float* vp = v + (size_t)bh * 16384;
    const float* mf = mfv + b * 1024;

    float qv[16];
    #pragma unroll
    for (int d = 0; d < 16; ++d) qv[d] = qp[d * 1024 + qi] * 0.25f;

    float acc[16];
    #pragma unroll
    for (int d = 0; d < 16; ++d) acc[d] = 0.f;
    float sum = 0.f;

    const int skey = t & 63, sd = t >> 6;

    {
        float a0 = kp[sd * 1024 + skey];
        float a1 = kp[(sd + 8) * 1024 + skey];
        float b0 = vp[sd * 1024 + skey];
        float b1 = vp[(sd + 8) * 1024 + skey];
        kt[0][skey * 20 + sd]     = a0;
        kt[0][skey * 20 + sd + 8] = a1;
        vt[0][skey * 20 + sd]     = b0;
        vt[0][skey * 20 + sd + 8] = b1;
        if (t < 64) mt[0][t] = mf[t];
    }
    __syncthreads();

    for (int tl = 0; tl < 16; ++tl) {
        const int cur = tl & 1;
        float pk0, pk1, pv0, pv1, pm;
        if (tl < 15) {
            int kb = (tl + 1) * 64;
            pk0 = kp[sd * 1024 + kb + skey];
            pk1 = kp[(sd + 8) * 1024 + kb + skey];
            pv0 = vp[sd * 1024 + kb + skey];
            pv1 = vp[(sd + 8) * 1024 + kb + skey];
            if (t < 64) pm = mf[kb + t];
        }
        const float* kbuf = kt[cur];
        const float* vbuf = vt[cur];
        const float* mbuf = mt[cur];
        #pragma unroll 2
        for (int kk = 0; kk < 64; ++kk) {
            const float4* kr = (const float4*)(kbuf + kk * 20);
            float4 k0 = kr[0], k1 = kr[1], k2 = kr[2], k3 = kr[3];
            float s0 =          qv[0]  * k0.x;
            float s1 =          qv[1]  * k0.y;
            float s2 =          qv[2]  * k0.z;
            float s3 =          qv[3]  * k0.w;
            s0 = fmaf(qv[4],  k1.x, s0); s1 = fmaf(qv[5],  k1.y, s1);
            s2 = fmaf(qv[6],  k1.z, s2); s3 = fmaf(qv[7],  k1.w, s3);
            s0 = fmaf(qv[8],  k2.x, s0); s1 = fmaf(qv[9],  k2.y, s1);
            s2 = fmaf(qv[10], k2.z, s2); s3 = fmaf(qv[11], k2.w, s3);
            s0 = fmaf(qv[12], k3.x, s0); s1 = fmaf(qv[13], k3.y, s1);
            s2 = fmaf(qv[14], k3.z, s2); s3 = fmaf(qv[15], k3.w, s3);
            float s = fminf((s0 + s1) + (s2 + s3), mbuf[kk]);
            float p = __expf(s);
            sum += p;
            const float4* vr = (const float4*)(vbuf + kk * 20);
            float4 v0 = vr[0], v1 = vr[1], v2 = vr[2], v3 = vr[3];
            acc[0]  = fmaf(p, v0.x, acc[0]);  acc[1]  = fmaf(p, v0.y, acc[1]);
            acc[2]  = fmaf(p, v0.z, acc[2]);  acc[3]  = fmaf(p, v0.w, acc[3]);
            acc[4]  = fmaf(p, v1.x, acc[4]);  acc[5]  = fmaf(p, v1.y, acc[5]);
            acc[6]  = fmaf(p, v1.z, acc[6]);  acc[7]  = fmaf(p, v1.w, acc[7]);
            acc[8]  = fmaf(p, v2.x, acc[8]);  acc[9]  = fmaf(p, v2.y, acc[9]);
            acc[10] = fmaf(p, v2.z, acc[10]); acc[11] = fmaf(p, v2.w, acc[11]);
            acc[12] = fmaf(p, v3.x, acc[12]); acc[13] = fmaf(p, v3.y, acc[13]);
            acc[14] = fmaf(p, v3.z, acc[14]); acc[15] = fmaf(p, v3.w, acc[15]);
        }
        __syncthreads();
        if (tl < 15) {
            const int nxt = cur ^ 1;
            kt[nxt][skey * 20 + sd]     = pk0;
            kt[nxt][skey * 20 + sd + 8] = pk1;
            vt[nxt][skey * 20 + sd]     = pv0;
            vt[nxt][skey * 20 + sd + 8] = pv1;
            if (t < 64) mt[nxt][t] = pm;
        }
        __syncthreads();
    }

    float inv = 1.0f / (sum + 1e-37f);
    float* op = ab + ((size_t)b * 128 + h * 16) * 1024 + qi;
    #pragma unroll
    for (int d = 0; d < 16; ++d) op[(size_t)d * 1024] = acc[d] * inv;
}

__global__ __launch_bounds__(512) void k_oproj(
    const float* __restrict__ in, const float* __restrict__ wT,
    const float* __restrict__ bo, const float* __restrict__ res,
    float* __restrict__ out)
{
    __shared__ float as[128 * 64];
    __shared__ float wlds[128 * 128];
    const int b  = blockIdx.x >> 4;
    const int l0 = (blockIdx.x & 15) << 6;
    const int t  = threadIdx.x;
    const int lane = t & 63;
    const int wv = t >> 6;
    const float* xb = in + b * 131072;

    {
        const float4* wsv = (const float4*)wT;
        float4* wd = (float4*)wlds;
        #pragma unroll
        for (int r = 0; r < 8; ++r) wd[t + r * 512] = wsv[t + r * 512];
    }
    for (int i = t; i < 8192; i += 512) {
        int c = i >> 6, col = i & 63;
        as[i] = xb[c * 1024 + l0 + col];
    }
    __syncthreads();

    const int ow = wv << 4;
    float acc[16];
    #pragma unroll
    for (int j = 0; j < 16; ++j) acc[j] = 0.f;
    #pragma unroll 4
    for (int c = 0; c < 128; ++c) {
        float y = as[c * 64 + lane];
        const float4* wr = (const float4*)(wlds + c * 128 + ow);
        float4 w0 = wr[0], w1 = wr[1], w2 = wr[2], w3 = wr[3];
        acc[0]  = fmaf(w0.x, y, acc[0]);  acc[1]  = fmaf(w0.y, y, acc[1]);
        acc[2]  = fmaf(w0.z, y, acc[2]);  acc[3]  = fmaf(w0.w, y, acc[3]);
        acc[4]  = fmaf(w1.x, y, acc[4]);  acc[5]  = fmaf(w1.y, y, acc[5]);
        acc[6]  = fmaf(w1.z, y, acc[6]);  acc[7]  = fmaf(w1.w, y, acc[7]);
        acc[8]  = fmaf(w2.x, y, acc[8]);  acc[9]  = fmaf(w2.y, y, acc[9]);
        acc[10] = fmaf(w2.z, y, acc[10]); acc[11] = fmaf(w2.w, y, acc[11]);
        acc[12] = fmaf(w3.x, y, acc[12]); acc[13] = fmaf(w3.y, y, acc[13]);
        acc[14] = fmaf(w3.z, y, acc[14]); acc[15] = fmaf(w3.w, y, acc[15]);
    }
    const float* rb = res + b * 131072;
    float* ob = out + b * 131072;
    #pragma unroll
    for (int j = 0; j < 16; ++j) {
        int o = ow + j;
        ob[o * 1024 + l0 + lane] = acc[j] + bo[o] + rb[o * 1024 + l0 + lane];
    }
}

__global__ __launch_bounds__(512) void k_ffn(
    const float* __restrict__ in,
    const float* __restrict__ w1T, const float* __restrict__ w2T,
    const float* __restrict__ b1, const float* __restrict__ b2,
    const float* __restrict__ g, const float* __restrict__ nbv,
    float* __restrict__ out)
{
    __shared__ float ln[128 * 64];
    __shared__ float wlds[128 * 128];
    __shared__ float part[64 * 8];
    __shared__ float muL[64], rsL[64];
    const int b  = blockIdx.x >> 4;
    const int l0 = (blockIdx.x & 15) << 6;
    const int t  = threadIdx.x;
    const int lane = t & 63;
    const int wv = t >> 6;
    const float* xb = in + b * 131072;

    {
        const float4* wsv = (const float4*)w1T;
        float4* wd = (float4*)wlds;
        #pragma unroll
        for (int r = 0; r < 8; ++r) wd[t + r * 512] = wsv[t + r * 512];
    }
    for (int i = t; i < 8192; i += 512) {
        int c = i >> 6, col = i & 63;
        ln[i] = xb[c * 1024 + l0 + col];
    }
    __syncthreads();
    if (t < 256) {
        int col = t >> 2, sl = t & 3;
        float s = 0.f, ss = 0.f;
        for (int c = sl * 32; c < sl * 32 + 32; ++c) {
            float v = ln[c * 64 + col];
            s += v; ss = fmaf(v, v, ss);
        }
        part[col * 8 + sl * 2]     = s;
        part[col * 8 + sl * 2 + 1] = ss;
    }
    __syncthreads();
    if (t < 64) {
        float s  = part[t*8] + part[t*8+2] + part[t*8+4] + part[t*8+6];
        float ss = part[t*8+1] + part[t*8+3] + part[t*8+5] + part[t*8+7];
        float mu = s * 0.0078125f;
        float var = ss * 0.0078125f - mu * mu;
        muL[t] = mu;
        rsL[t] = rsqrtf(var + 1e-5f);
    }
    __syncthreads();
    for (int k = 0; k < 16; ++k) {
        int c = (t >> 6) + k * 8;
        float v = ln[c * 64 + lane];
        ln[c * 64 + lane] = (v - muL[lane]) * rsL[lane] * g[c] + nbv[c];
    }
    __syncthreads();

    const int ow = wv << 4;
    float4 pw[8];
    {
        const float4* wsv = (const float4*)w2T;
        #pragma unroll
        for (int r = 0; r < 8; ++r) pw[r] = wsv[t + r * 512];
    }
    float acc[16];
    #pragma unroll
    for (int j = 0; j < 16; ++j) acc[j] = 0.f;
    #pragma unroll 4
    for (int c = 0; c < 128; ++c) {
        float y = ln[c * 64 + lane];
        const float4* wr = (const float4*)(wlds + c * 128 + ow);
        float4 w0 = wr[0], w1 = wr[1], w2 = wr[2], w3 = wr[3];
        acc[0]  = fmaf(w0.x, y, acc[0]);  acc[1]  = fmaf(w0.y, y, acc[1]);
        acc[2]  = fmaf(w0.z, y, acc[2]);  acc[3]  = fmaf(w0.w, y, acc[3]);
        acc[4]  = fmaf(w1.x, y, acc[4]);  acc[5]  = fmaf(w1.y, y, acc[5]);
        acc[6]  = fmaf(w1.z, y, acc[6]);  acc[7]  = fmaf(w1.w, y, acc[7]);
        acc[8]  = fmaf(w2.x, y, acc[8]);  acc[9]  = fmaf(w2.y, y, acc[9]);
        acc[10] = fmaf(w2.z, y, acc[10]); acc[11] = fmaf(w2.w, y, acc[11]);
        acc[12] = fmaf(w3.x, y, acc[12]); acc[13] = fmaf(w3.y, y, acc[13]);
        acc[14] = fmaf(w3.z, y, acc[14]); acc[15] = fmaf(w3.w, y, acc[15]);
    }
    __syncthreads();
    #pragma unroll
    for (int j = 0; j < 16; ++j)
        ln[(ow + j) * 64 + lane] = fmaxf(acc[j] + b1[ow + j], 0.f);
    {
        float4* wd = (float4*)wlds;
        #pragma unroll
        for (int r = 0; r < 8; ++r) wd[t + r * 512] = pw[r];
    }
    __syncthreads();
    #pragma unroll
    for (int j = 0; j < 16; ++j) acc[j] = 0.f;
    #pragma unroll 4
    for (int c = 0; c < 128; ++c) {
        float y = ln[c * 64 + lane];
        const float4* wr = (const float4*)(wlds + c * 128 + ow);
        float4 w0 = wr[0], w1 = wr[1], w2 = wr[2], w3 = wr[3];
        acc[0]  = fmaf(w0.x, y, acc[0]);  acc[1]  = fmaf(w0.y, y, acc[1]);
        acc[2]  = fmaf(w0.z, y, acc[2]);  acc[3]  = fmaf(w0.w, y, acc[3]);
        acc[4]  = fmaf(w1.x, y, acc[4]);  acc[5]  = fmaf(w1.y, y, acc[5]);
        acc[6]  = fmaf(w1.z, y, acc[6]);  acc[7]  = fmaf(w1.w, y, acc[7]);
        acc[8]  = fmaf(w2.x, y, acc[8]);  acc[9]  = fmaf(w2.y, y, acc[9]);
        acc[10] = fmaf(w2.z, y, acc[10]); acc[11] = fmaf(w2.w, y, acc[11]);
        acc[12] = fmaf(w3.x, y, acc[12]); acc[13] = fmaf(w3.y, y, acc[13]);
        acc[14] = fmaf(w3.z, y, acc[14]); acc[15] = fmaf(w3.w, y, acc[15]);
    }
    float* ob = out + b * 131072;
    #pragma unroll
    for (int j = 0; j < 16; ++j) {
        int o = ow + j;
        ob[o * 1024 + l0 + lane] = acc[j] + b2[o] + xb[o * 1024 + l0 + lane];
    }
}

extern "C" void kernel_launch(void* const* d_in, const int* in_sizes, int n_in,
                              void* d_out, int out_size, void* d_ws, size_t ws_size,
                              hipStream_t stream)
{
    const float* x    = (const float*)d_in[0];
    const unsigned char* mask = (const unsigned char*)d_in[1];
    const float* dw_w = (const float*)d_in[2];
    const float* pw_w = (const float*)d_in[3];
    const float* pw_b = (const float*)d_in[4];
    const float* ng   = (const float*)d_in[5];
    const float* nb   = (const float*)d_in[6];
    const float* wq   = (const float*)d_in[7];
    const float* bq   = (const float*)d_in[8];
    const float* wk   = (const float*)d_in[9];
    const float* bk   = (const float*)d_in[10];
    const float* wv   = (const float*)d_in[11];
    const float* bv   = (const float*)d_in[12];
    const float* wo   = (const float*)d_in[13];
    const float* bo   = (const float*)d_in[14];
    const float* w1   = (const float*)d_in[15];
    const float* b1   = (const float*)d_in[16];
    const float* w2   = (const float*)d_in[17];
    const float* b2   = (const float*)d_in[18];

    float* ws   = (float*)d_ws;
    float* act0 = ws + OFF_ACT0;
    float* act1 = ws + OFF_ACT1;
    float* qw   = ws + OFF_QW;
    float* kw   = ws + OFF_KW;
    float* vw   = ws + OFF_VW;
    float* ab   = ws + OFF_AB;
    float* wT   = ws + OFF_WT;
    float* mf   = ws + OFF_MF;
    float* dw8  = ws + OFF_DW8;

    k_prep<<<49, 256, 0, stream>>>(pw_w, wq, wk, wv, wo, w1, w2, mask, dw_w,
                                   wT, mf, dw8);
    k_pe<<<8192, 256, 0, stream>>>(x, act0);

    k_conv<<<256, 512, 0, stream>>>(act0, act1, wT + 0 * 16384, dw8 + 0,
                                    pw_b + 0,   ng + 0,   nb + 0);
    k_conv<<<256, 512, 0, stream>>>(act1, act0, wT + 1 * 16384, dw8 + 1024,
                                    pw_b + 128, ng + 128, nb + 128);
    k_conv<<<256, 512, 0, stream>>>(act0, act1, wT + 2 * 16384, dw8 + 2048,
                                    pw_b + 256, ng + 256, nb + 256);
    k_conv<<<256, 512, 0, stream>>>(act1, act0, wT + 3 * 16384, dw8 + 3072,
                                    pw_b + 384, ng + 384, nb + 384);

    k_qkv<<<256, 512, 0, stream>>>(act0, wT + 4 * 16384, bq, bk, bv,
                                   ng + 4 * 128, nb + 4 * 128, qw, kw, vw);
    k_attn<<<256, 512, 0, stream>>>(qw, kw, vw, mf, ab);
    k_oproj<<<256, 512, 0, stream>>>(ab, wT + 7 * 16384, bo, act0, act1);
    k_ffn<<<256, 512, 0, stream>>>(act1, wT + 8 * 16384, wT + 9 * 16384,
                                   b1, b2, ng + 5 * 128, nb + 5 * 128,
                                   (float*)d_out);
}

// Round 4
// 391.486 us; speedup vs baseline: 2.0409x; 1.3323x over previous
//
#include <hip/hip_runtime.h>
#include <math.h>

// ---------------------------------------------------------------------------
// EncoderBlock fp32+bf16-MFMA, MI355X. B=16,C=128,L=1024,H=8,DK=16,K=7,NCONV=4
// R3 change: attention rewritten with bf16 MFMA (32x32x16 QK^T-swapped +
// 16x16x32 PV), K/V staged in LDS, per-wave LDS P-bounce, no-max softmax
// with {0,1} mask multiplier. k_qkv emits bf16 q/k ([bh][l][16], 0.25 folded
// into q) and v ([bh][16][l]); k_prep emits mask multiplier. All other
// kernels identical to R2 for attribution.
// ---------------------------------------------------------------------------

#define ACT_N   2097152
#define OFF_ACT0 0
#define OFF_ACT1 (ACT_N)
#define OFF_QW   (2*ACT_N)
#define OFF_KW   (3*ACT_N)
#define OFF_VW   (4*ACT_N)
#define OFF_AB   (5*ACT_N)
#define OFF_WT   (6*ACT_N)
#define OFF_MF   (6*ACT_N + 10*16384)
#define OFF_DW8  (6*ACT_N + 10*16384 + 16384)

typedef __attribute__((ext_vector_type(8)))  short bf16x8;
typedef __attribute__((ext_vector_type(16))) float f32x16;
typedef __attribute__((ext_vector_type(4)))  float f32x4;

static __device__ __forceinline__ unsigned int f2bf_rtne(float f) {
    unsigned int u = __float_as_uint(f);
    return (u + 0x7fffu + ((u >> 16) & 1u)) >> 16;
}

// ---------------------------------------------------------------------------
// k_prep: blocks 0..39 transpose 10 mats; 40..47 mask multiplier; 48 dw8
// ---------------------------------------------------------------------------
__global__ __launch_bounds__(256) void k_prep(
    const float* __restrict__ pw, const float* __restrict__ wq,
    const float* __restrict__ wk, const float* __restrict__ wv_,
    const float* __restrict__ wo, const float* __restrict__ w1,
    const float* __restrict__ w2, const unsigned char* __restrict__ mask,
    const float* __restrict__ dwsrc,
    float* __restrict__ wT, float* __restrict__ maskf, float* __restrict__ dw8)
{
    __shared__ float td[32][33];
    int blk = blockIdx.x;
    int t = threadIdx.x;
    if (blk < 40) {
        int mat = blk >> 2, og = blk & 3;
        const float* src;
        if (mat < 4)      src = pw + mat * 16384;
        else if (mat == 4) src = wq;
        else if (mat == 5) src = wk;
        else if (mat == 6) src = wv_;
        else if (mat == 7) src = wo;
        else if (mat == 8) src = w1;
        else               src = w2;
        float* dst = wT + mat * 16384;
        for (int cg = 0; cg < 4; ++cg) {
            for (int i = t; i < 1024; i += 256) {
                int o = i >> 5, c = i & 31;
                td[o][c] = src[(og * 32 + o) * 128 + cg * 32 + c];
            }
            __syncthreads();
            for (int i = t; i < 1024; i += 256) {
                int c = i >> 5, oo = i & 31;
                dst[(cg * 32 + c) * 128 + og * 32 + oo] = td[oo][c];
            }
            __syncthreads();
        }
    } else if (blk < 48) {
        int base = (blk - 40) * 2048;
        for (int i = t; i < 2048; i += 256)
            maskf[base + i] = mask[base + i] ? 0.0f : 1.0f;   // multiplier
    } else {
        for (int i = t; i < 4096; i += 256) {
            int n = i >> 3, tap = i & 7;
            dw8[i] = (tap < 7) ? dwsrc[n * 7 + tap] : 0.0f;
        }
    }
}

__global__ __launch_bounds__(256) void k_pe(const float* __restrict__ x,
                                            float* __restrict__ out)
{
    int idx = blockIdx.x * 256 + threadIdx.x;
    int l = idx & 1023;
    int c = (idx >> 10) & 127;
    float e = (float)(c & ~1);
    float base = exp2f(e * (-13.287712379549449f / 128.0f));
    float freq = (c & 1) ? -base : base;
    float ph   = (c & 1) ? 1.5707963267948966f : 0.0f;
    out[idx] = x[idx] + sinf((float)l * freq + ph);
}

// ---------------------------------------------------------------------------
// k_conv (unchanged from R2)
// ---------------------------------------------------------------------------
__global__ __launch_bounds__(512) void k_conv(
    const float* __restrict__ in, float* __restrict__ out,
    const float* __restrict__ wT, const float* __restrict__ dw8,
    const float* __restrict__ pb,
    const float* __restrict__ g, const float* __restrict__ nbv)
{
    __shared__ float xs[128 * 70];
    __shared__ float wlds[128 * 128];
    __shared__ float dwl[128 * 8];
    __shared__ float part[70 * 8];
    __shared__ float muL[70], rsL[70];
    const int b  = blockIdx.x >> 4;
    const int l0 = (blockIdx.x & 15) << 6;
    const int t  = threadIdx.x;
    const int lane = t & 63;
    const int wv = t >> 6;
    const float* xb = in + b * 131072;

    {
        const float4* wsv = (const float4*)wT;
        float4* wd = (float4*)wlds;
        #pragma unroll
        for (int r = 0; r < 8; ++r) wd[t + r * 512] = wsv[t + r * 512];
        if (t < 256) ((float4*)dwl)[t] = ((const float4*)dw8)[t];
    }
    for (int i = t; i < 8960; i += 512) {
        int c = i / 70;
        int col = i - c * 70;
        int gl = l0 - 3 + col;
        xs[i] = ((unsigned)gl < 1024u) ? xb[c * 1024 + gl] : 0.0f;
    }
    __syncthreads();

    if (t < 280) {
        int col = t >> 2, sl = t & 3;
        float s = 0.f, ss = 0.f;
        for (int c = sl * 32; c < sl * 32 + 32; ++c) {
            float v = xs[c * 70 + col];
            s += v; ss = fmaf(v, v, ss);
        }
        part[col * 8 + sl * 2]     = s;
        part[col * 8 + sl * 2 + 1] = ss;
    }
    __syncthreads();
    if (t < 70) {
        float s  = part[t*8] + part[t*8+2] + part[t*8+4] + part[t*8+6];
        float ss = part[t*8+1] + part[t*8+3] + part[t*8+5] + part[t*8+7];
        float mu = s * 0.0078125f;
        float var = ss * 0.0078125f - mu * mu;
        muL[t] = mu;
        rsL[t] = rsqrtf(var + 1e-5f);
    }
    __syncthreads();
    for (int c = wv; c < 128; c += 8) {
        float gg = g[c], bb = nbv[c];
        int gl = l0 - 3 + lane;
        if ((unsigned)gl < 1024u) {
            float v = xs[c * 70 + lane];
            xs[c * 70 + lane] = (v - muL[lane]) * rsL[lane] * gg + bb;
        }
        if (lane < 6) {
            int col = 64 + lane;
            int gl2 = l0 - 3 + col;
            if ((unsigned)gl2 < 1024u) {
                float v = xs[c * 70 + col];
                xs[c * 70 + col] = (v - muL[col]) * rsL[col] * gg + bb;
            }
        }
    }
    __syncthreads();

    const int ow = wv << 4;
    float acc[16];
    #pragma unroll
    for (int j = 0; j < 16; ++j) acc[j] = 0.f;
    #pragma unroll 4
    for (int c = 0; c < 128; ++c) {
        const float* xr = xs + c * 70 + lane;
        const float4* dr = (const float4*)(dwl + c * 8);
        float4 d0 = dr[0], d1 = dr[1];
        float y =          d0.x * xr[0];
        y = fmaf(d0.y, xr[1], y);
        y = fmaf(d0.z, xr[2], y);
        y = fmaf(d0.w, xr[3], y);
        y = fmaf(d1.x, xr[4], y);
        y = fmaf(d1.y, xr[5], y);
        y = fmaf(d1.z, xr[6], y);
        const float4* wr = (const float4*)(wlds + c * 128 + ow);
        float4 w0 = wr[0], w1 = wr[1], w2 = wr[2], w3 = wr[3];
        acc[0]  = fmaf(w0.x, y, acc[0]);  acc[1]  = fmaf(w0.y, y, acc[1]);
        acc[2]  = fmaf(w0.z, y, acc[2]);  acc[3]  = fmaf(w0.w, y, acc[3]);
        acc[4]  = fmaf(w1.x, y, acc[4]);  acc[5]  = fmaf(w1.y, y, acc[5]);
        acc[6]  = fmaf(w1.z, y, acc[6]);  acc[7]  = fmaf(w1.w, y, acc[7]);
        acc[8]  = fmaf(w2.x, y, acc[8]);  acc[9]  = fmaf(w2.y, y, acc[9]);
        acc[10] = fmaf(w2.z, y, acc[10]); acc[11] = fmaf(w2.w, y, acc[11]);
        acc[12] = fmaf(w3.x, y, acc[12]); acc[13] = fmaf(w3.y, y, acc[13]);
        acc[14] = fmaf(w3.z, y, acc[14]); acc[15] = fmaf(w3.w, y, acc[15]);
    }

    float* ob = out + b * 131072;
    #pragma unroll
    for (int j = 0; j < 16; ++j) {
        int o = ow + j;
        float v = fmaxf(acc[j] + pb[o], 0.f) + xb[o * 1024 + l0 + lane];
        ob[o * 1024 + l0 + lane] = v;
    }
}

// ---------------------------------------------------------------------------
// k_qkv: LN + 3 fp32 GEMMs -> bf16 outputs:
//   qb [bh][q][16] (0.25 folded), kb [bh][k][16], vt [bh][16][k]
// ---------------------------------------------------------------------------
__global__ __launch_bounds__(512) void k_qkv(
    const float* __restrict__ in, const float* __restrict__ wT,
    const float* __restrict__ bq, const float* __restrict__ bk,
    const float* __restrict__ bv,
    const float* __restrict__ g, const float* __restrict__ nbv,
    unsigned short* __restrict__ qb, unsigned short* __restrict__ kb,
    unsigned short* __restrict__ vt)
{
    __shared__ float ln[128 * 64];
    __shared__ float wlds[128 * 128];
    __shared__ float part[64 * 8];
    __shared__ float muL[64], rsL[64];
    const int b  = blockIdx.x >> 4;
    const int l0 = (blockIdx.x & 15) << 6;
    const int t  = threadIdx.x;
    const int lane = t & 63;
    const int wv = t >> 6;
    const float* xb = in + b * 131072;

    {
        const float4* wsv = (const float4*)wT;
        float4* wd = (float4*)wlds;
        #pragma unroll
        for (int r = 0; r < 8; ++r) wd[t + r * 512] = wsv[t + r * 512];
    }
    for (int i = t; i < 8192; i += 512) {
        int c = i >> 6, col = i & 63;
        ln[i] = xb[c * 1024 + l0 + col];
    }
    __syncthreads();
    if (t < 256) {
        int col = t >> 2, sl = t & 3;
        float s = 0.f, ss = 0.f;
        for (int c = sl * 32; c < sl * 32 + 32; ++c) {
            float v = ln[c * 64 + col];
            s += v; ss = fmaf(v, v, ss);
        }
        part[col * 8 + sl * 2]     = s;
        part[col * 8 + sl * 2 + 1] = ss;
    }
    __syncthreads();
    if (t < 64) {
        float s  = part[t*8] + part[t*8+2] + part[t*8+4] + part[t*8+6];
        float ss = part[t*8+1] + part[t*8+3] + part[t*8+5] + part[t*8+7];
        float mu = s * 0.0078125f;
        float var = ss * 0.0078125f - mu * mu;
        muL[t] = mu;
        rsL[t] = rsqrtf(var + 1e-5f);
    }
    __syncthreads();
    for (int k = 0; k < 16; ++k) {
        int c = (t >> 6) + k * 8;
        float v = ln[c * 64 + lane];
        ln[c * 64 + lane] = (v - muL[lane]) * rsL[lane] * g[c] + nbv[c];
    }
    __syncthreads();

    const int ow = wv << 4;
    for (int p = 0; p < 3; ++p) {
        const float* bias = (p == 0) ? bq : (p == 1) ? bk : bv;
        float4 pw[8];
        if (p < 2) {
            const float4* wsv = (const float4*)(wT + (p + 1) * 16384);
            #pragma unroll
            for (int r = 0; r < 8; ++r) pw[r] = wsv[t + r * 512];
        }
        float acc[16];
        #pragma unroll
        for (int j = 0; j < 16; ++j) acc[j] = 0.f;
        #pragma unroll 4
        for (int c = 0; c < 128; ++c) {
            float y = ln[c * 64 + lane];
            const float4* wr = (const float4*)(wlds + c * 128 + ow);
            float4 w0 = wr[0], w1 = wr[1], w2 = wr[2], w3 = wr[3];
            acc[0]  = fmaf(w0.x, y, acc[0]);  acc[1]  = fmaf(w0.y, y, acc[1]);
            acc[2]  = fmaf(w0.z, y, acc[2]);  acc[3]  = fmaf(w0.w, y, acc[3]);
            acc[4]  = fmaf(w1.x, y, acc[4]);  acc[5]  = fmaf(w1.y, y, acc[5]);
            acc[6]  = fmaf(w1.z, y, acc[6]);  acc[7]  = fmaf(w1.w, y, acc[7]);
            acc[8]  = fmaf(w2.x, y, acc[8]);  acc[9]  = fmaf(w2.y, y, acc[9]);
            acc[10] = fmaf(w2.z, y, acc[10]); acc[11] = fmaf(w2.w, y, acc[11]);
            acc[12] = fmaf(w3.x, y, acc[12]); acc[13] = fmaf(w3.y, y, acc[13]);
            acc[14] = fmaf(w3.z, y, acc[14]); acc[15] = fmaf(w3.w, y, acc[15]);
        }
        const int bh = b * 8 + wv;
        if (p < 2) {
            const float scl = (p == 0) ? 0.25f : 1.0f;
            unsigned short* dst = (p == 0) ? qb : kb;
            unsigned int w8[8];
            #pragma unroll
            for (int jj = 0; jj < 8; ++jj) {
                float v0 = (acc[2*jj]   + bias[ow + 2*jj])   * scl;
                float v1 = (acc[2*jj+1] + bias[ow + 2*jj+1]) * scl;
                w8[jj] = f2bf_rtne(v0) | (f2bf_rtne(v1) << 16);
            }
            uint4* o4 = (uint4*)(dst + ((size_t)bh * 1024 + l0 + lane) * 16);
            uint4 a, bb2;
            a.x = w8[0]; a.y = w8[1]; a.z = w8[2]; a.w = w8[3];
            bb2.x = w8[4]; bb2.y = w8[5]; bb2.z = w8[6]; bb2.w = w8[7];
            o4[0] = a; o4[1] = bb2;
        } else {
            #pragma unroll
            for (int j = 0; j < 16; ++j) {
                float v0 = acc[j] + bias[ow + j];
                vt[((size_t)bh * 16 + j) * 1024 + l0 + lane] =
                    (unsigned short)f2bf_rtne(v0);
            }
        }
        __syncthreads();
        if (p < 2) {
            float4* wd = (float4*)wlds;
            #pragma unroll
            for (int r = 0; r < 8; ++r) wd[t + r * 512] = pw[r];
        }
        __syncthreads();
    }
}

// ---------------------------------------------------------------------------
// k_attn (R3): bf16 MFMA. grid 1024 = 128 bh x 8 q-groups(128), 256 thr.
// Wave = 32 queries. Per 32-key chunk: S^T = mfma_32x32x16(K,Q) ->
// lane-local softmax (no-max, mask multiplier) -> P bf16 via per-wave LDS
// bounce -> 2x mfma_16x16x32(P, V^T). LDS layouts conflict-free by design.
// ---------------------------------------------------------------------------
__global__ __launch_bounds__(256) void k_attn(
    const unsigned short* __restrict__ qb, const unsigned short* __restrict__ kb,
    const unsigned short* __restrict__ vt, const float* __restrict__ mmul,
    float* __restrict__ ab)
{
    __shared__ unsigned int Kl[8192];        // [1024 keys][16 bf16] = 32KB
    __shared__ unsigned int Vl[8256];        // [16 d][1032 bf16]   = 33KB
    __shared__ float        Ml[1024];        // mask multiplier
    __shared__ unsigned int Pl[4][640];      // per-wave P / O scratch (2560B)

    const int bh = blockIdx.x >> 3;
    const int b  = bh >> 3;
    const int h  = bh & 7;
    const int qbase = (blockIdx.x & 7) << 7;
    const int t = threadIdx.x;
    const int lane = t & 63;
    const int w = t >> 6;

    // ---- stage K (linear), V (rows padded to 1032), mask ----
    {
        const uint4* ksrc = (const uint4*)(kb + (size_t)bh * 16384);
        uint4* kdst = (uint4*)Kl;
        #pragma unroll
        for (int i = 0; i < 8; ++i) kdst[t + i * 256] = ksrc[t + i * 256];
        const unsigned short* vsrc = vt + (size_t)bh * 16384;
        #pragma unroll
        for (int i = 0; i < 8; ++i) {
            int idx = t + i * 256;
            int d = idx >> 7, c = idx & 127;
            uint4 val = *(const uint4*)(vsrc + d * 1024 + c * 8);
            *(uint4*)((char*)Vl + d * 2064 + c * 16) = val;
        }
        ((float4*)Ml)[t] = ((const float4*)(mmul + b * 1024))[t];
    }
    __syncthreads();

    const int l31 = lane & 31, hi = lane >> 5;
    const int l15 = lane & 15, h2 = lane >> 4;
    const int qw = qbase + w * 32;

    bf16x8 qf;
    {
        uint4 qv = *(const uint4*)(qb + ((size_t)bh * 1024 + qw + l31) * 16 + hi * 8);
        union { uint4 u; bf16x8 v; } cvt; cvt.u = qv; qf = cvt.v;
    }

    f32x16 Z;
    #pragma unroll
    for (int i = 0; i < 16; ++i) Z[i] = 0.f;
    f32x4 O0, O1;
    #pragma unroll
    for (int i = 0; i < 4; ++i) { O0[i] = 0.f; O1[i] = 0.f; }
    float sum = 0.f;

    unsigned int* myP = &Pl[w][0];

    for (int kc = 0; kc < 32; ++kc) {
        bf16x8 kf = *(const bf16x8*)((const char*)Kl + (kc * 32 + l31) * 32 + hi * 16);
        f32x16 S = __builtin_amdgcn_mfma_f32_32x32x16_bf16(kf, qf, Z, 0, 0, 0);

        #pragma unroll
        for (int rg = 0; rg < 4; ++rg) {
            float4 mm = *(const float4*)(Ml + kc * 32 + rg * 8 + hi * 4);
            float p0 = __expf(S[rg * 4 + 0]) * mm.x;
            float p1 = __expf(S[rg * 4 + 1]) * mm.y;
            float p2 = __expf(S[rg * 4 + 2]) * mm.z;
            float p3 = __expf(S[rg * 4 + 3]) * mm.w;
            sum += (p0 + p1) + (p2 + p3);
            uint2 pwd;   // RTZ pack: (hi16 of p1 | hi16 of p0)
            pwd.x = (__float_as_uint(p1) & 0xffff0000u) | (__float_as_uint(p0) >> 16);
            pwd.y = (__float_as_uint(p3) & 0xffff0000u) | (__float_as_uint(p2) >> 16);
            *(uint2*)((char*)myP + l31 * 80 + rg * 16 + hi * 8) = pwd;
        }

        bf16x8 vf  = *(const bf16x8*)((const char*)Vl + l15 * 2064 + kc * 64 + h2 * 16);
        bf16x8 pa0 = *(const bf16x8*)((const char*)myP + l15 * 80 + h2 * 16);
        bf16x8 pa1 = *(const bf16x8*)((const char*)myP + (16 + l15) * 80 + h2 * 16);
        O0 = __builtin_amdgcn_mfma_f32_16x16x32_bf16(pa0, vf, O0, 0, 0, 0);
        O1 = __builtin_amdgcn_mfma_f32_16x16x32_bf16(pa1, vf, O1, 0, 0, 0);
    }

    sum += __shfl_xor(sum, 32);
    float inv = 1.0f / sum;

    // olds bounce (reuse myP as f32 [32 q][stride 17])
    #pragma unroll
    for (int r = 0; r < 4; ++r) {
        float iv0 = __shfl(inv, h2 * 4 + r);
        float iv1 = __shfl(inv, 16 + h2 * 4 + r);
        myP[(h2 * 4 + r) * 17 + l15]      = __float_as_uint(O0[r] * iv0);
        myP[(16 + h2 * 4 + r) * 17 + l15] = __float_as_uint(O1[r] * iv1);
    }

    float* abase = ab + ((size_t)(b * 128 + h * 16)) * 1024 + qw;
    #pragma unroll
    for (int jj = 0; jj < 8; ++jj) {
        int d = (jj << 1) + hi;
        float val = __uint_as_float(myP[l31 * 17 + d]);
        abase[(size_t)d * 1024 + l31] = val;
    }
}

// ---------------------------------------------------------------------------
// k_oproj (unchanged)
// ---------------------------------------------------------------------------
__global__ __launch_bounds__(512) void k_oproj(
    const float* __restrict__ in, const float* __restrict__ wT,
    const float* __restrict__ bo, const float* __restrict__ res,
    float* __restrict__ out)
{
    __shared__ float as[128 * 64];
    __shared__ float wlds[128 * 128];
    const int b  = blockIdx.x >> 4;
    const int l0 = (blockIdx.x & 15) << 6;
    const int t  = threadIdx.x;
    const int lane = t & 63;
    const int wv = t >> 6;
    const float* xb = in + b * 131072;

    {
        const float4* wsv = (const float4*)wT;
        float4* wd = (float4*)wlds;
        #pragma unroll
        for (int r = 0; r < 8; ++r) wd[t + r * 512] = wsv[t + r * 512];
    }
    for (int i = t; i < 8192; i += 512) {
        int c = i >> 6, col = i & 63;
        as[i] = xb[c * 1024 + l0 + col];
    }
    __syncthreads();

    const int ow = wv << 4;
    float acc[16];
    #pragma unroll
    for (int j = 0; j < 16; ++j) acc[j] = 0.f;
    #pragma unroll 4
    for (int c = 0; c < 128; ++c) {
        float y = as[c * 64 + lane];
        const float4* wr = (const float4*)(wlds + c * 128 + ow);
        float4 w0 = wr[0], w1 = wr[1], w2 = wr[2], w3 = wr[3];
        acc[0]  = fmaf(w0.x, y, acc[0]);  acc[1]  = fmaf(w0.y, y, acc[1]);
        acc[2]  = fmaf(w0.z, y, acc[2]);  acc[3]  = fmaf(w0.w, y, acc[3]);
        acc[4]  = fmaf(w1.x, y, acc[4]);  acc[5]  = fmaf(w1.y, y, acc[5]);
        acc[6]  = fmaf(w1.z, y, acc[6]);  acc[7]  = fmaf(w1.w, y, acc[7]);
        acc[8]  = fmaf(w2.x, y, acc[8]);  acc[9]  = fmaf(w2.y, y, acc[9]);
        acc[10] = fmaf(w2.z, y, acc[10]); acc[11] = fmaf(w2.w, y, acc[11]);
        acc[12] = fmaf(w3.x, y, acc[12]); acc[13] = fmaf(w3.y, y, acc[13]);
        acc[14] = fmaf(w3.z, y, acc[14]); acc[15] = fmaf(w3.w, y, acc[15]);
    }
    const float* rb = res + b * 131072;
    float* ob = out + b * 131072;
    #pragma unroll
    for (int j = 0; j < 16; ++j) {
        int o = ow + j;
        ob[o * 1024 + l0 + lane] = acc[j] + bo[o] + rb[o * 1024 + l0 + lane];
    }
}

// ---------------------------------------------------------------------------
// k_ffn (unchanged)
// ---------------------------------------------------------------------------
__global__ __launch_bounds__(512) void k_ffn(
    const float* __restrict__ in,
    const float* __restrict__ w1T, const float* __restrict__ w2T,
    const float* __restrict__ b1, const float* __restrict__ b2,
    const float* __restrict__ g, const float* __restrict__ nbv,
    float* __restrict__ out)
{
    __shared__ float ln[128 * 64];
    __shared__ float wlds[128 * 128];
    __shared__ float part[64 * 8];
    __shared__ float muL[64], rsL[64];
    const int b  = blockIdx.x >> 4;
    const int l0 = (blockIdx.x & 15) << 6;
    const int t  = threadIdx.x;
    const int lane = t & 63;
    const int wv = t >> 6;
    const float* xb = in + b * 131072;

    {
        const float4* wsv = (const float4*)w1T;
        float4* wd = (float4*)wlds;
        #pragma unroll
        for (int r = 0; r < 8; ++r) wd[t + r * 512] = wsv[t + r * 512];
    }
    for (int i = t; i < 8192; i += 512) {
        int c = i >> 6, col = i & 63;
        ln[i] = xb[c * 1024 + l0 + col];
    }
    __syncthreads();
    if (t < 256) {
        int col = t >> 2, sl = t & 3;
        float s = 0.f, ss = 0.f;
        for (int c = sl * 32; c < sl * 32 + 32; ++c) {
            float v = ln[c * 64 + col];
            s += v; ss = fmaf(v, v, ss);
        }
        part[col * 8 + sl * 2]     = s;
        part[col * 8 + sl * 2 + 1] = ss;
    }
    __syncthreads();
    if (t < 64) {
        float s  = part[t*8] + part[t*8+2] + part[t*8+4] + part[t*8+6];
        float ss = part[t*8+1] + part[t*8+3] + part[t*8+5] + part[t*8+7];
        float mu = s * 0.0078125f;
        float var = ss * 0.0078125f - mu * mu;
        muL[t] = mu;
        rsL[t] = rsqrtf(var + 1e-5f);
    }
    __syncthreads();
    for (int k = 0; k < 16; ++k) {
        int c = (t >> 6) + k * 8;
        float v = ln[c * 64 + lane];
        ln[c * 64 + lane] = (v - muL[lane]) * rsL[lane] * g[c] + nbv[c];
    }
    __syncthreads();

    const int ow = wv << 4;
    float4 pw[8];
    {
        const float4* wsv = (const float4*)w2T;
        #pragma unroll
        for (int r = 0; r < 8; ++r) pw[r] = wsv[t + r * 512];
    }
    float acc[16];
    #pragma unroll
    for (int j = 0; j < 16; ++j) acc[j] = 0.f;
    #pragma unroll 4
    for (int c = 0; c < 128; ++c) {
        float y = ln[c * 64 + lane];
        const float4* wr = (const float4*)(wlds + c * 128 + ow);
        float4 w0 = wr[0], w1 = wr[1], w2 = wr[2], w3 = wr[3];
        acc[0]  = fmaf(w0.x, y, acc[0]);  acc[1]  = fmaf(w0.y, y, acc[1]);
        acc[2]  = fmaf(w0.z, y, acc[2]);  acc[3]  = fmaf(w0.w, y, acc[3]);
        acc[4]  = fmaf(w1.x, y, acc[4]);  acc[5]  = fmaf(w1.y, y, acc[5]);
        acc[6]  = fmaf(w1.z, y, acc[6]);  acc[7]  = fmaf(w1.w, y, acc[7]);
        acc[8]  = fmaf(w2.x, y, acc[8]);  acc[9]  = fmaf(w2.y, y, acc[9]);
        acc[10] = fmaf(w2.z, y, acc[10]); acc[11] = fmaf(w2.w, y, acc[11]);
        acc[12] = fmaf(w3.x, y, acc[12]); acc[13] = fmaf(w3.y, y, acc[13]);
        acc[14] = fmaf(w3.z, y, acc[14]); acc[15] = fmaf(w3.w, y, acc[15]);
    }
    __syncthreads();
    #pragma unroll
    for (int j = 0; j < 16; ++j)
        ln[(ow + j) * 64 + lane] = fmaxf(acc[j] + b1[ow + j], 0.f);
    {
        float4* wd = (float4*)wlds;
        #pragma unroll
        for (int r = 0; r < 8; ++r) wd[t + r * 512] = pw[r];
    }
    __syncthreads();
    #pragma unroll
    for (int j = 0; j < 16; ++j) acc[j] = 0.f;
    #pragma unroll 4
    for (int c = 0; c < 128; ++c) {
        float y = ln[c * 64 + lane];
        const float4* wr = (const float4*)(wlds + c * 128 + ow);
        float4 w0 = wr[0], w1 = wr[1], w2 = wr[2], w3 = wr[3];
        acc[0]  = fmaf(w0.x, y, acc[0]);  acc[1]  = fmaf(w0.y, y, acc[1]);
        acc[2]  = fmaf(w0.z, y, acc[2]);  acc[3]  = fmaf(w0.w, y, acc[3]);
        acc[4]  = fmaf(w1.x, y, acc[4]);  acc[5]  = fmaf(w1.y, y, acc[5]);
        acc[6]  = fmaf(w1.z, y, acc[6]);  acc[7]  = fmaf(w1.w, y, acc[7]);
        acc[8]  = fmaf(w2.x, y, acc[8]);  acc[9]  = fmaf(w2.y, y, acc[9]);
        acc[10] = fmaf(w2.z, y, acc[10]); acc[11] = fmaf(w2.w, y, acc[11]);
        acc[12] = fmaf(w3.x, y, acc[12]); acc[13] = fmaf(w3.y, y, acc[13]);
        acc[14] = fmaf(w3.z, y, acc[14]); acc[15] = fmaf(w3.w, y, acc[15]);
    }
    float* ob = out + b * 131072;
    #pragma unroll
    for (int j = 0; j < 16; ++j) {
        int o = ow + j;
        ob[o * 1024 + l0 + lane] = acc[j] + b2[o] + xb[o * 1024 + l0 + lane];
    }
}

// ---------------------------------------------------------------------------
extern "C" void kernel_launch(void* const* d_in, const int* in_sizes, int n_in,
                              void* d_out, int out_size, void* d_ws, size_t ws_size,
                              hipStream_t stream)
{
    const float* x    = (const float*)d_in[0];
    const unsigned char* mask = (const unsigned char*)d_in[1];
    const float* dw_w = (const float*)d_in[2];
    const float* pw_w = (const float*)d_in[3];
    const float* pw_b = (const float*)d_in[4];
    const float* ng   = (const float*)d_in[5];
    const float* nb   = (const float*)d_in[6];
    const float* wq   = (const float*)d_in[7];
    const float* bq   = (const float*)d_in[8];
    const float* wk   = (const float*)d_in[9];
    const float* bk   = (const float*)d_in[10];
    const float* wv   = (const float*)d_in[11];
    const float* bv   = (const float*)d_in[12];
    const float* wo   = (const float*)d_in[13];
    const float* bo   = (const float*)d_in[14];
    const float* w1   = (const float*)d_in[15];
    const float* b1   = (const float*)d_in[16];
    const float* w2   = (const float*)d_in[17];
    const float* b2   = (const float*)d_in[18];

    float* ws   = (float*)d_ws;
    float* act0 = ws + OFF_ACT0;
    float* act1 = ws + OFF_ACT1;
    unsigned short* qb = (unsigned short*)(ws + OFF_QW);
    unsigned short* kbp = (unsigned short*)(ws + OFF_KW);
    unsigned short* vtp = (unsigned short*)(ws + OFF_VW);
    float* ab   = ws + OFF_AB;
    float* wT   = ws + OFF_WT;
    float* mf   = ws + OFF_MF;
    float* dw8  = ws + OFF_DW8;

    k_prep<<<49, 256, 0, stream>>>(pw_w, wq, wk, wv, wo, w1, w2, mask, dw_w,
                                   wT, mf, dw8);
    k_pe<<<8192, 256, 0, stream>>>(x, act0);

    k_conv<<<256, 512, 0, stream>>>(act0, act1, wT + 0 * 16384, dw8 + 0,
                                    pw_b + 0,   ng + 0,   nb + 0);
    k_conv<<<256, 512, 0, stream>>>(act1, act0, wT + 1 * 16384, dw8 + 1024,
                                    pw_b + 128, ng + 128, nb + 128);
    k_conv<<<256, 512, 0, stream>>>(act0, act1, wT + 2 * 16384, dw8 + 2048,
                                    pw_b + 256, ng + 256, nb + 256);
    k_conv<<<256, 512, 0, stream>>>(act1, act0, wT + 3 * 16384, dw8 + 3072,
                                    pw_b + 384, ng + 384, nb + 384);

    k_qkv<<<256, 512, 0, stream>>>(act0, wT + 4 * 16384, bq, bk, bv,
                                   ng + 4 * 128, nb + 4 * 128, qb, kbp, vtp);
    k_attn<<<1024, 256, 0, stream>>>(qb, kbp, vtp, mf, ab);
    k_oproj<<<256, 512, 0, stream>>>(ab, wT + 7 * 16384, bo, act0, act1);
    k_ffn<<<256, 512, 0, stream>>>(act1, wT + 8 * 16384, wT + 9 * 16384,
                                   b1, b2, ng + 5 * 128, nb + 5 * 128,
                                   (float*)d_out);
}

// Round 5
// 224.336 us; speedup vs baseline: 3.5616x; 1.7451x over previous
//
#include <hip/hip_runtime.h>
#include <math.h>

// ---------------------------------------------------------------------------
// EncoderBlock, MI355X. B=16,C=128,L=1024,H=8,DK=16,K=7,NCONV=4.
// R4: ALL channel-mixing GEMMs converted to bf16 MFMA (32x32x16), using the
// fragment layouts verified by R3's passing attention. LN/depthwise/softmax/
// residual stay fp32. q/k stored in MFMA-native permuted d-order (QK^T is
// invariant under consistent d-permutation). Attention emits bf16 [l][128]
// directly consumed by O-proj.
// ---------------------------------------------------------------------------

#define ACT_N   2097152
#define OFF_ACT0 0
#define OFF_ACT1 (ACT_N)
#define OFF_QB   (2*ACT_N)   // u16[16384*16]
#define OFF_KB   (3*ACT_N)
#define OFF_VT   (4*ACT_N)
#define OFF_ABF  (5*ACT_N)   // u16[16384*128]
#define OFF_MF   (6*ACT_N)
#define OFF_WB   (6*ACT_N + 16384)            // u16[10*16384]
#define OFF_DW8  (6*ACT_N + 16384 + 81920)    // float[4096]

typedef __attribute__((ext_vector_type(8)))  short bf16x8;
typedef __attribute__((ext_vector_type(16))) float f32x16;
typedef __attribute__((ext_vector_type(4)))  float f32x4;

static __device__ __forceinline__ unsigned int f2bf(float f) {
    unsigned int u = __float_as_uint(f);
    return (u + 0x7fffu + ((u >> 16) & 1u)) >> 16;
}
static __device__ __forceinline__ unsigned int pk2(float a, float b) {
    return f2bf(a) | (f2bf(b) << 16);
}

// swizzled byte offset of 16B granule g in row `row` of a [*][128 bf16] tile
#define GOFF(row, g) (((row) << 8) + ((((g) ^ ((row) & 15))) << 4))

// ---------------------------------------------------------------------------
// k_prep: 0..9 convert 10 weight mats fp32->bf16 [o][c]; 10 mask mult; 11 dw8
// ---------------------------------------------------------------------------
__global__ __launch_bounds__(256) void k_prep(
    const float* __restrict__ pw, const float* __restrict__ wq,
    const float* __restrict__ wk, const float* __restrict__ wv_,
    const float* __restrict__ wo, const float* __restrict__ w1,
    const float* __restrict__ w2, const unsigned char* __restrict__ mask,
    const float* __restrict__ dwsrc,
    unsigned short* __restrict__ wb, float* __restrict__ maskf,
    float* __restrict__ dw8)
{
    int blk = blockIdx.x, t = threadIdx.x;
    if (blk < 10) {
        const float* src;
        if (blk < 4)       src = pw + blk * 16384;
        else if (blk == 4) src = wq;
        else if (blk == 5) src = wk;
        else if (blk == 6) src = wv_;
        else if (blk == 7) src = wo;
        else if (blk == 8) src = w1;
        else               src = w2;
        unsigned short* dst = wb + blk * 16384;
        for (int i = t * 8; i < 16384; i += 2048) {
            float4 a = *(const float4*)(src + i);
            float4 c = *(const float4*)(src + i + 4);
            uint4 v;
            v.x = pk2(a.x, a.y); v.y = pk2(a.z, a.w);
            v.z = pk2(c.x, c.y); v.w = pk2(c.z, c.w);
            *(uint4*)(dst + i) = v;
        }
    } else if (blk == 10) {
        for (int i = t; i < 16384; i += 256)
            maskf[i] = mask[i] ? 0.0f : 1.0f;
    } else {
        for (int i = t; i < 4096; i += 256) {
            int n = i >> 3, tap = i & 7;
            dw8[i] = (tap < 7) ? dwsrc[n * 7 + tap] : 0.0f;
        }
    }
}

__global__ __launch_bounds__(256) void k_pe(const float* __restrict__ x,
                                            float* __restrict__ out)
{
    int idx = blockIdx.x * 256 + threadIdx.x;
    int l = idx & 1023;
    int c = (idx >> 10) & 127;
    float e = (float)(c & ~1);
    float base = exp2f(e * (-13.287712379549449f / 128.0f));
    float freq = (c & 1) ? -base : base;
    float ph   = (c & 1) ? 1.5707963267948966f : 0.0f;
    out[idx] = x[idx] + sinf((float)l * freq + ph);
}

// ---------------------------------------------------------------------------
// k_conv: LN -> depthwise (fp32, fused) -> bf16 MFMA pointwise -> ReLU -> +res
// 256 blocks x 512 thr (8 waves). Wave = (o-tile w>>1, l-half w&1).
// ---------------------------------------------------------------------------
__global__ __launch_bounds__(512) void k_conv(
    const float* __restrict__ in, float* __restrict__ out,
    const unsigned short* __restrict__ wb,   // bf16 [128 o][128 c]
    const float* __restrict__ dw8,           // [128][8]
    const float* __restrict__ pb,
    const float* __restrict__ g, const float* __restrict__ nbv)
{
    __shared__ unsigned short Wl[16384];     // 32KB swizzled
    __shared__ unsigned short Xl[8192];      // 16KB [64 l][128 c] swizzled
    __shared__ float part[560];
    __shared__ float muL[70], rsL[70];

    const int b  = blockIdx.x >> 4;
    const int l0 = (blockIdx.x & 15) << 6;
    const int t  = threadIdx.x;
    const int lane = t & 63;
    const int w = __builtin_amdgcn_readfirstlane(t >> 6);
    const float* xb = in + b * 131072;

    // stage weights: 2048 granules, 4/thread, swizzled dst
    {
        const uint4* src = (const uint4*)wb;
        #pragma unroll
        for (int i = 0; i < 4; ++i) {
            int gi = t + i * 512;
            uint4 v = src[gi];
            int row = gi >> 4, c16 = gi & 15;
            *(uint4*)((char*)Wl + GOFF(row, c16)) = v;
        }
    }
    // LN stats over 70 cols (halo of 3 each side)
    if (t < 280) {
        int col = t >> 2, sl = t & 3;
        int gl = l0 - 3 + col;
        float s = 0.f, ss = 0.f;
        if ((unsigned)gl < 1024u) {
            for (int c = sl * 32; c < sl * 32 + 32; ++c) {
                float v = xb[c * 1024 + gl];
                s += v; ss = fmaf(v, v, ss);
            }
        }
        part[col * 8 + sl * 2]     = s;
        part[col * 8 + sl * 2 + 1] = ss;
    }
    __syncthreads();
    if (t < 70) {
        int gl = l0 - 3 + t;
        if ((unsigned)gl < 1024u) {
            float s  = part[t*8] + part[t*8+2] + part[t*8+4] + part[t*8+6];
            float ss = part[t*8+1] + part[t*8+3] + part[t*8+5] + part[t*8+7];
            float mu = s * 0.0078125f;
            float var = ss * 0.0078125f - mu * mu;
            muL[t] = mu; rsL[t] = rsqrtf(var + 1e-5f);
        } else { muL[t] = 0.f; rsL[t] = 0.f; }
    }
    __syncthreads();

    // depthwise + LN fused, pack bf16 -> Xl. thread: l=lane, c-strips of 8
    {
        const int l = lane;
        const int gl = l0 + l;
        float m[7], rf[7], vm[7];
        int pofs[7];
        #pragma unroll
        for (int j = 0; j < 7; ++j) {
            int p = gl - 3 + j;
            m[j]  = muL[l + j];
            rf[j] = rsL[l + j];
            vm[j] = ((unsigned)p < 1024u) ? 1.f : 0.f;
            pofs[j] = min(max(p, 0), 1023);
        }
        #pragma unroll
        for (int s = 0; s < 2; ++s) {
            int c0 = w * 16 + s * 8;
            unsigned int pk[4];
            #pragma unroll
            for (int cp = 0; cp < 4; ++cp) {
                float y2[2];
                #pragma unroll
                for (int ci = 0; ci < 2; ++ci) {
                    int c = c0 + cp * 2 + ci;
                    const float* xr = xb + c * 1024;
                    const float* dr = dw8 + c * 8;
                    float S1 = 0.f, S2 = 0.f;
                    #pragma unroll
                    for (int j = 0; j < 7; ++j) {
                        float xv = xr[pofs[j]];
                        float u = (xv - m[j]) * rf[j];
                        float dwv = dr[j];
                        S1 = fmaf(dwv, u,     S1);
                        S2 = fmaf(dwv, vm[j], S2);
                    }
                    y2[ci] = g[c] * S1 + nbv[c] * S2;
                }
                pk[cp] = pk2(y2[0], y2[1]);
            }
            *(uint4*)((char*)Xl + GOFF(l, (c0 >> 3))) = *(uint4*)pk;
        }
    }
    __syncthreads();

    // MFMA: wave (ow, lh) computes D[32 o][32 l]
    const int l31 = lane & 31, hi = lane >> 5;
    const int ow = w >> 1, lh = w & 1;
    bf16x8 af[8];
    #pragma unroll
    for (int kc = 0; kc < 8; ++kc)
        af[kc] = *(const bf16x8*)((char*)Wl + GOFF(ow * 32 + l31, kc * 2 + hi));
    f32x16 acc;
    #pragma unroll
    for (int i = 0; i < 16; ++i) acc[i] = 0.f;
    #pragma unroll
    for (int kc = 0; kc < 8; ++kc) {
        bf16x8 bx = *(const bf16x8*)((char*)Xl + GOFF(lh * 32 + l31, kc * 2 + hi));
        acc = __builtin_amdgcn_mfma_f32_32x32x16_bf16(af[kc], bx, acc, 0, 0, 0);
    }
    float* ob = out + b * 131072;
    const int lg = l0 + lh * 32 + l31;
    #pragma unroll
    for (int r = 0; r < 16; ++r) {
        int o = ow * 32 + (r & 3) + 8 * (r >> 2) + 4 * hi;
        ob[o * 1024 + lg] = fmaxf(acc[r] + pb[o], 0.f) + xb[o * 1024 + lg];
    }
}

// ---------------------------------------------------------------------------
// k_qkv: LN -> 3 bf16 MFMA GEMMs.
//   q/k -> [bh][l][16 slots] bf16 (MFMA-native permuted d, 0.25 folded in q)
//   v   -> [bh][16 d][1024]  bf16 (logical d, via per-wave LDS transpose)
// ---------------------------------------------------------------------------
__global__ __launch_bounds__(512) void k_qkv(
    const float* __restrict__ in, const unsigned short* __restrict__ wb,
    const float* __restrict__ bq, const float* __restrict__ bk,
    const float* __restrict__ bv,
    const float* __restrict__ g, const float* __restrict__ nbv,
    unsigned short* __restrict__ qb, unsigned short* __restrict__ kb,
    unsigned short* __restrict__ vt)
{
    __shared__ unsigned short Wl[16384];
    __shared__ unsigned short Xl[8192];
    __shared__ unsigned short vs[8][1280];   // per-wave [32 d][40 l]
    __shared__ float part[1024];
    __shared__ float muL[64], rsL[64];

    const int b  = blockIdx.x >> 4;
    const int l0 = (blockIdx.x & 15) << 6;
    const int t  = threadIdx.x;
    const int lane = t & 63;
    const int w = __builtin_amdgcn_readfirstlane(t >> 6);
    const float* xb = in + b * 131072;

    {
        const uint4* src = (const uint4*)wb;    // wq
        #pragma unroll
        for (int i = 0; i < 4; ++i) {
            int gi = t + i * 512;
            uint4 v = src[gi];
            int row = gi >> 4, c16 = gi & 15;
            *(uint4*)((char*)Wl + GOFF(row, c16)) = v;
        }
    }
    {   // stats: 8 threads/col
        int col = t >> 3, sl = t & 7;
        float s = 0.f, ss = 0.f;
        for (int c = sl * 16; c < sl * 16 + 16; ++c) {
            float v = xb[c * 1024 + l0 + col];
            s += v; ss = fmaf(v, v, ss);
        }
        part[col * 16 + sl * 2]     = s;
        part[col * 16 + sl * 2 + 1] = ss;
    }
    __syncthreads();
    if (t < 64) {
        float s = 0.f, ss = 0.f;
        #pragma unroll
        for (int j = 0; j < 8; ++j) { s += part[t*16 + j*2]; ss += part[t*16 + j*2 + 1]; }
        float mu = s * 0.0078125f;
        float var = ss * 0.0078125f - mu * mu;
        muL[t] = mu; rsL[t] = rsqrtf(var + 1e-5f);
    }
    __syncthreads();
    {   // LN apply + pack -> Xl. thread: l=lane, c-strips
        const int l = lane;
        float mu = muL[l], rs = rsL[l];
        #pragma unroll
        for (int s = 0; s < 2; ++s) {
            int c0 = w * 16 + s * 8;
            unsigned int pk[4];
            #pragma unroll
            for (int cp = 0; cp < 4; ++cp) {
                int c = c0 + cp * 2;
                float v0 = (xb[c * 1024 + l0 + l]       - mu) * rs * g[c]     + nbv[c];
                float v1 = (xb[(c + 1) * 1024 + l0 + l] - mu) * rs * g[c + 1] + nbv[c + 1];
                pk[cp] = pk2(v0, v1);
            }
            *(uint4*)((char*)Xl + GOFF(l, (c0 >> 3))) = *(uint4*)pk;
        }
    }
    __syncthreads();

    const int l31 = lane & 31, hi = lane >> 5;
    const int ow = w >> 1, lh = w & 1;
    const int lg = l0 + lh * 32 + l31;

    for (int p = 0; p < 3; ++p) {
        uint4 pw4[4];
        if (p < 2) {
            const uint4* src = (const uint4*)(wb + (p + 1) * 16384);
            #pragma unroll
            for (int i = 0; i < 4; ++i) pw4[i] = src[t + i * 512];
        }
        bf16x8 af[8];
        #pragma unroll
        for (int kc = 0; kc < 8; ++kc)
            af[kc] = *(const bf16x8*)((char*)Wl + GOFF(ow * 32 + l31, kc * 2 + hi));
        f32x16 acc;
        #pragma unroll
        for (int i = 0; i < 16; ++i) acc[i] = 0.f;
        #pragma unroll
        for (int kc = 0; kc < 8; ++kc) {
            bf16x8 bx = *(const bf16x8*)((char*)Xl + GOFF(lh * 32 + l31, kc * 2 + hi));
            acc = __builtin_amdgcn_mfma_f32_32x32x16_bf16(af[kc], bx, acc, 0, 0, 0);
        }

        if (p < 2) {
            const float* bias = (p == 0) ? bq : bk;
            unsigned short* dst = (p == 0) ? qb : kb;
            const float scl = (p == 0) ? 0.25f : 1.0f;
            unsigned int pk0[4], pk1[4];
            #pragma unroll
            for (int j2 = 0; j2 < 4; ++j2) {
                int r = j2 * 2;
                int o0 = ow * 32 + (r & 3) + 8 * (r >> 2) + 4 * hi;
                pk0[j2] = pk2((acc[r] + bias[o0]) * scl,
                              (acc[r + 1] + bias[o0 + 1]) * scl);
                int r8 = r + 8;
                int o1 = ow * 32 + (r8 & 3) + 8 * (r8 >> 2) + 4 * hi;
                pk1[j2] = pk2((acc[r8] + bias[o1]) * scl,
                              (acc[r8 + 1] + bias[o1 + 1]) * scl);
            }
            int bh0 = b * 8 + 2 * ow;
            *(uint4*)(dst + ((size_t)bh0 * 1024 + lg) * 16 + hi * 8) = *(uint4*)pk0;
            *(uint4*)(dst + ((size_t)(bh0 + 1) * 1024 + lg) * 16 + hi * 8) = *(uint4*)pk1;
        } else {
            // v: transpose via per-wave scratch (odd-ish 40-u16 row stride)
            unsigned short* vsw = vs[w];
            #pragma unroll
            for (int r = 0; r < 16; ++r) {
                int orow = (r & 3) + 8 * (r >> 2) + 4 * hi;
                int o = ow * 32 + orow;
                vsw[orow * 40 + l31] = (unsigned short)f2bf(acc[r] + bv[o]);
            }
            int d32 = l31;
            uint4 v0 = *(uint4*)(vsw + d32 * 40 + hi * 16);
            uint4 v1 = *(uint4*)(vsw + d32 * 40 + hi * 16 + 8);
            int head = 2 * ow + (d32 >> 4), dd = d32 & 15;
            unsigned short* vp = vt + ((size_t)(b * 8 + head) * 16 + dd) * 1024
                                    + l0 + lh * 32 + hi * 16;
            *(uint4*)vp = v0; *(uint4*)(vp + 8) = v1;
        }
        __syncthreads();
        if (p < 2) {
            #pragma unroll
            for (int i = 0; i < 4; ++i) {
                int gi = t + i * 512;
                int row = gi >> 4, c16 = gi & 15;
                *(uint4*)((char*)Wl + GOFF(row, c16)) = pw4[i];
            }
            __syncthreads();
        }
    }
}

// ---------------------------------------------------------------------------
// k_attn (R3 structure, unchanged math): outputs bf16 [b*1024+l][128] -> abf
// ---------------------------------------------------------------------------
__global__ __launch_bounds__(256) void k_attn(
    const unsigned short* __restrict__ qb, const unsigned short* __restrict__ kb,
    const unsigned short* __restrict__ vt, const float* __restrict__ mmul,
    unsigned short* __restrict__ abf)
{
    __shared__ unsigned int Kl[8192];
    __shared__ unsigned int Vl[8256];
    __shared__ float        Ml[1024];
    __shared__ unsigned int Pl[4][640];

    const int bh = blockIdx.x >> 3;
    const int b  = bh >> 3;
    const int h  = bh & 7;
    const int qbase = (blockIdx.x & 7) << 7;
    const int t = threadIdx.x;
    const int lane = t & 63;
    const int w = t >> 6;

    {
        const uint4* ksrc = (const uint4*)(kb + (size_t)bh * 16384);
        uint4* kdst = (uint4*)Kl;
        #pragma unroll
        for (int i = 0; i < 8; ++i) kdst[t + i * 256] = ksrc[t + i * 256];
        const unsigned short* vsrc = vt + (size_t)bh * 16384;
        #pragma unroll
        for (int i = 0; i < 8; ++i) {
            int idx = t + i * 256;
            int d = idx >> 7, c = idx & 127;
            uint4 val = *(const uint4*)(vsrc + d * 1024 + c * 8);
            *(uint4*)((char*)Vl + d * 2064 + c * 16) = val;
        }
        ((float4*)Ml)[t] = ((const float4*)(mmul + b * 1024))[t];
    }
    __syncthreads();

    const int l31 = lane & 31, hi = lane >> 5;
    const int l15 = lane & 15, h2 = lane >> 4;
    const int qw = qbase + w * 32;

    bf16x8 qf;
    {
        uint4 qv = *(const uint4*)(qb + ((size_t)bh * 1024 + qw + l31) * 16 + hi * 8);
        union { uint4 u; bf16x8 v; } cvt; cvt.u = qv; qf = cvt.v;
    }

    f32x16 Z;
    #pragma unroll
    for (int i = 0; i < 16; ++i) Z[i] = 0.f;
    f32x4 O0, O1;
    #pragma unroll
    for (int i = 0; i < 4; ++i) { O0[i] = 0.f; O1[i] = 0.f; }
    float sum = 0.f;

    unsigned int* myP = &Pl[w][0];

    for (int kc = 0; kc < 32; ++kc) {
        bf16x8 kf = *(const bf16x8*)((const char*)Kl + (kc * 32 + l31) * 32 + hi * 16);
        f32x16 S = __builtin_amdgcn_mfma_f32_32x32x16_bf16(kf, qf, Z, 0, 0, 0);

        #pragma unroll
        for (int rg = 0; rg < 4; ++rg) {
            float4 mm = *(const float4*)(Ml + kc * 32 + rg * 8 + hi * 4);
            float p0 = __expf(S[rg * 4 + 0]) * mm.x;
            float p1 = __expf(S[rg * 4 + 1]) * mm.y;
            float p2 = __expf(S[rg * 4 + 2]) * mm.z;
            float p3 = __expf(S[rg * 4 + 3]) * mm.w;
            sum += (p0 + p1) + (p2 + p3);
            uint2 pwd;
            pwd.x = (__float_as_uint(p1) & 0xffff0000u) | (__float_as_uint(p0) >> 16);
            pwd.y = (__float_as_uint(p3) & 0xffff0000u) | (__float_as_uint(p2) >> 16);
            *(uint2*)((char*)myP + l31 * 80 + rg * 16 + hi * 8) = pwd;
        }

        bf16x8 vf  = *(const bf16x8*)((const char*)Vl + l15 * 2064 + kc * 64 + h2 * 16);
        bf16x8 pa0 = *(const bf16x8*)((const char*)myP + l15 * 80 + h2 * 16);
        bf16x8 pa1 = *(const bf16x8*)((const char*)myP + (16 + l15) * 80 + h2 * 16);
        O0 = __builtin_amdgcn_mfma_f32_16x16x32_bf16(pa0, vf, O0, 0, 0, 0);
        O1 = __builtin_amdgcn_mfma_f32_16x16x32_bf16(pa1, vf, O1, 0, 0, 0);
    }

    sum += __shfl_xor(sum, 32);
    float inv = 1.0f / sum;

    #pragma unroll
    for (int r = 0; r < 4; ++r) {
        float iv0 = __shfl(inv, h2 * 4 + r);
        float iv1 = __shfl(inv, 16 + h2 * 4 + r);
        myP[(h2 * 4 + r) * 17 + l15]      = __float_as_uint(O0[r] * iv0);
        myP[(16 + h2 * 4 + r) * 17 + l15] = __float_as_uint(O1[r] * iv1);
    }
    unsigned int pk4[4];
    #pragma unroll
    for (int j2 = 0; j2 < 4; ++j2) {
        float a0 = __uint_as_float(myP[l31 * 17 + hi * 8 + j2 * 2]);
        float a1 = __uint_as_float(myP[l31 * 17 + hi * 8 + j2 * 2 + 1]);
        pk4[j2] = pk2(a0, a1);
    }
    unsigned short* op = abf + ((size_t)(b * 1024 + qw + l31)) * 128 + h * 16 + hi * 8;
    *(uint4*)op = *(uint4*)pk4;
}

// ---------------------------------------------------------------------------
// k_oproj: bf16 MFMA GEMM(wo) + bias + residual -> fp32
// ---------------------------------------------------------------------------
__global__ __launch_bounds__(512) void k_oproj(
    const unsigned short* __restrict__ abf, const unsigned short* __restrict__ wb,
    const float* __restrict__ bo, const float* __restrict__ res,
    float* __restrict__ out)
{
    __shared__ unsigned short Wl[16384];
    __shared__ unsigned short Xl[8192];
    const int b  = blockIdx.x >> 4;
    const int l0 = (blockIdx.x & 15) << 6;
    const int t  = threadIdx.x;
    const int lane = t & 63;
    const int w = __builtin_amdgcn_readfirstlane(t >> 6);

    {
        const uint4* src = (const uint4*)wb;
        #pragma unroll
        for (int i = 0; i < 4; ++i) {
            int gi = t + i * 512;
            uint4 v = src[gi];
            int row = gi >> 4, c16 = gi & 15;
            *(uint4*)((char*)Wl + GOFF(row, c16)) = v;
        }
        #pragma unroll
        for (int i = 0; i < 2; ++i) {
            int gi = t + i * 512;
            int row = gi >> 4, c16 = gi & 15;
            uint4 v = *(const uint4*)(abf + ((size_t)(b * 1024 + l0 + row)) * 128 + c16 * 8);
            *(uint4*)((char*)Xl + GOFF(row, c16)) = v;
        }
    }
    __syncthreads();

    const int l31 = lane & 31, hi = lane >> 5;
    const int ow = w >> 1, lh = w & 1;
    bf16x8 af[8];
    #pragma unroll
    for (int kc = 0; kc < 8; ++kc)
        af[kc] = *(const bf16x8*)((char*)Wl + GOFF(ow * 32 + l31, kc * 2 + hi));
    f32x16 acc;
    #pragma unroll
    for (int i = 0; i < 16; ++i) acc[i] = 0.f;
    #pragma unroll
    for (int kc = 0; kc < 8; ++kc) {
        bf16x8 bx = *(const bf16x8*)((char*)Xl + GOFF(lh * 32 + l31, kc * 2 + hi));
        acc = __builtin_amdgcn_mfma_f32_32x32x16_bf16(af[kc], bx, acc, 0, 0, 0);
    }
    const float* rb = res + b * 131072;
    float* ob = out + b * 131072;
    const int lg = l0 + lh * 32 + l31;
    #pragma unroll
    for (int r = 0; r < 16; ++r) {
        int o = ow * 32 + (r & 3) + 8 * (r >> 2) + 4 * hi;
        ob[o * 1024 + lg] = acc[r] + bo[o] + rb[o * 1024 + lg];
    }
}

// ---------------------------------------------------------------------------
// k_ffn: LN -> MFMA GEMM(w1)+ReLU -> MFMA GEMM(w2) + b2 + residual -> d_out
// ---------------------------------------------------------------------------
__global__ __launch_bounds__(512) void k_ffn(
    const float* __restrict__ in,
    const unsigned short* __restrict__ w1b, const unsigned short* __restrict__ w2b,
    const float* __restrict__ b1, const float* __restrict__ b2,
    const float* __restrict__ g, const float* __restrict__ nbv,
    float* __restrict__ out)
{
    __shared__ unsigned short Wl[16384];
    __shared__ unsigned short Xl[8192];
    __shared__ unsigned short Xl2[8192];
    __shared__ float part[1024];
    __shared__ float muL[64], rsL[64];

    const int b  = blockIdx.x >> 4;
    const int l0 = (blockIdx.x & 15) << 6;
    const int t  = threadIdx.x;
    const int lane = t & 63;
    const int w = __builtin_amdgcn_readfirstlane(t >> 6);
    const float* xb = in + b * 131072;

    {
        const uint4* src = (const uint4*)w1b;
        #pragma unroll
        for (int i = 0; i < 4; ++i) {
            int gi = t + i * 512;
            uint4 v = src[gi];
            int row = gi >> 4, c16 = gi & 15;
            *(uint4*)((char*)Wl + GOFF(row, c16)) = v;
        }
    }
    {
        int col = t >> 3, sl = t & 7;
        float s = 0.f, ss = 0.f;
        for (int c = sl * 16; c < sl * 16 + 16; ++c) {
            float v = xb[c * 1024 + l0 + col];
            s += v; ss = fmaf(v, v, ss);
        }
        part[col * 16 + sl * 2]     = s;
        part[col * 16 + sl * 2 + 1] = ss;
    }
    __syncthreads();
    if (t < 64) {
        float s = 0.f, ss = 0.f;
        #pragma unroll
        for (int j = 0; j < 8; ++j) { s += part[t*16 + j*2]; ss += part[t*16 + j*2 + 1]; }
        float mu = s * 0.0078125f;
        float var = ss * 0.0078125f - mu * mu;
        muL[t] = mu; rsL[t] = rsqrtf(var + 1e-5f);
    }
    __syncthreads();
    {
        const int l = lane;
        float mu = muL[l], rs = rsL[l];
        #pragma unroll
        for (int s = 0; s < 2; ++s) {
            int c0 = w * 16 + s * 8;
            unsigned int pk[4];
            #pragma unroll
            for (int cp = 0; cp < 4; ++cp) {
                int c = c0 + cp * 2;
                float v0 = (xb[c * 1024 + l0 + l]       - mu) * rs * g[c]     + nbv[c];
                float v1 = (xb[(c + 1) * 1024 + l0 + l] - mu) * rs * g[c + 1] + nbv[c + 1];
                pk[cp] = pk2(v0, v1);
            }
            *(uint4*)((char*)Xl + GOFF(l, (c0 >> 3))) = *(uint4*)pk;
        }
    }
    __syncthreads();

    const int l31 = lane & 31, hi = lane >> 5;
    const int ow = w >> 1, lh = w & 1;
    const int lrow = lh * 32 + l31;

    uint4 pw4[4];
    {
        const uint4* src = (const uint4*)w2b;
        #pragma unroll
        for (int i = 0; i < 4; ++i) pw4[i] = src[t + i * 512];
    }
    // GEMM1
    {
        bf16x8 af[8];
        #pragma unroll
        for (int kc = 0; kc < 8; ++kc)
            af[kc] = *(const bf16x8*)((char*)Wl + GOFF(ow * 32 + l31, kc * 2 + hi));
        f32x16 acc;
        #pragma unroll
        for (int i = 0; i < 16; ++i) acc[i] = 0.f;
        #pragma unroll
        for (int kc = 0; kc < 8; ++kc) {
            bf16x8 bx = *(const bf16x8*)((char*)Xl + GOFF(lrow, kc * 2 + hi));
            acc = __builtin_amdgcn_mfma_f32_32x32x16_bf16(af[kc], bx, acc, 0, 0, 0);
        }
        // h = relu(acc + b1) -> Xl2 (bf16, swizzled scatter)
        #pragma unroll
        for (int r = 0; r < 16; ++r) {
            int o = ow * 32 + (r & 3) + 8 * (r >> 2) + 4 * hi;
            float hval = fmaxf(acc[r] + b1[o], 0.f);
            *(unsigned short*)((char*)Xl2 + (lrow << 8)
                + ((((o >> 3) ^ (lrow & 15))) << 4) + ((o & 7) * 2)) =
                (unsigned short)f2bf(hval);
        }
    }
    __syncthreads();
    {
        #pragma unroll
        for (int i = 0; i < 4; ++i) {
            int gi = t + i * 512;
            int row = gi >> 4, c16 = gi & 15;
            *(uint4*)((char*)Wl + GOFF(row, c16)) = pw4[i];
        }
    }
    __syncthreads();
    // GEMM2
    {
        bf16x8 af[8];
        #pragma unroll
        for (int kc = 0; kc < 8; ++kc)
            af[kc] = *(const bf16x8*)((char*)Wl + GOFF(ow * 32 + l31, kc * 2 + hi));
        f32x16 acc;
        #pragma unroll
        for (int i = 0; i < 16; ++i) acc[i] = 0.f;
        #pragma unroll
        for (int kc = 0; kc < 8; ++kc) {
            bf16x8 bx = *(const bf16x8*)((char*)Xl2 + GOFF(lrow, kc * 2 + hi));
            acc = __builtin_amdgcn_mfma_f32_32x32x16_bf16(af[kc], bx, acc, 0, 0, 0);
        }
        float* ob = out + b * 131072;
        const int lg = l0 + lrow;
        #pragma unroll
        for (int r = 0; r < 16; ++r) {
            int o = ow * 32 + (r & 3) + 8 * (r >> 2) + 4 * hi;
            ob[o * 1024 + lg] = acc[r] + b2[o] + xb[o * 1024 + lg];
        }
    }
}

// ---------------------------------------------------------------------------
extern "C" void kernel_launch(void* const* d_in, const int* in_sizes, int n_in,
                              void* d_out, int out_size, void* d_ws, size_t ws_size,
                              hipStream_t stream)
{
    const float* x    = (const float*)d_in[0];
    const unsigned char* mask = (const unsigned char*)d_in[1];
    const float* dw_w = (const float*)d_in[2];
    const float* pw_w = (const float*)d_in[3];
    const float* pw_b = (const float*)d_in[4];
    const float* ng   = (const float*)d_in[5];
    const float* nb   = (const float*)d_in[6];
    const float* wq   = (const float*)d_in[7];
    const float* bq   = (const float*)d_in[8];
    const float* wk   = (const float*)d_in[9];
    const float* bk   = (const float*)d_in[10];
    const float* wv   = (const float*)d_in[11];
    const float* bv   = (const float*)d_in[12];
    const float* wo   = (const float*)d_in[13];
    const float* bo   = (const float*)d_in[14];
    const float* w1   = (const float*)d_in[15];
    const float* b1   = (const float*)d_in[16];
    const float* w2   = (const float*)d_in[17];
    const float* b2   = (const float*)d_in[18];

    float* ws   = (float*)d_ws;
    float* act0 = ws + OFF_ACT0;
    float* act1 = ws + OFF_ACT1;
    unsigned short* qb  = (unsigned short*)(ws + OFF_QB);
    unsigned short* kbp = (unsigned short*)(ws + OFF_KB);
    unsigned short* vtp = (unsigned short*)(ws + OFF_VT);
    unsigned short* abf = (unsigned short*)(ws + OFF_ABF);
    float* mf   = ws + OFF_MF;
    unsigned short* wb = (unsigned short*)(ws + OFF_WB);
    float* dw8  = ws + OFF_DW8;

    k_prep<<<12, 256, 0, stream>>>(pw_w, wq, wk, wv, wo, w1, w2, mask, dw_w,
                                   wb, mf, dw8);
    k_pe<<<8192, 256, 0, stream>>>(x, act0);

    k_conv<<<256, 512, 0, stream>>>(act0, act1, wb + 0 * 16384, dw8 + 0,
                                    pw_b + 0,   ng + 0,   nb + 0);
    k_conv<<<256, 512, 0, stream>>>(act1, act0, wb + 1 * 16384, dw8 + 1024,
                                    pw_b + 128, ng + 128, nb + 128);
    k_conv<<<256, 512, 0, stream>>>(act0, act1, wb + 2 * 16384, dw8 + 2048,
                                    pw_b + 256, ng + 256, nb + 256);
    k_conv<<<256, 512, 0, stream>>>(act1, act0, wb + 3 * 16384, dw8 + 3072,
                                    pw_b + 384, ng + 384, nb + 384);

    k_qkv<<<256, 512, 0, stream>>>(act0, wb + 4 * 16384, bq, bk, bv,
                                   ng + 4 * 128, nb + 4 * 128, qb, kbp, vtp);
    k_attn<<<1024, 256, 0, stream>>>(qb, kbp, vtp, mf, abf);
    k_oproj<<<256, 512, 0, stream>>>(abf, wb + 7 * 16384, bo, act0, act1);
    k_ffn<<<256, 512, 0, stream>>>(act1, wb + 8 * 16384, wb + 9 * 16384,
                                   b1, b2, ng + 5 * 128, nb + 5 * 128,
                                   (float*)d_out);
}